// Round 9
// baseline (1408.171 us; speedup 1.0000x reference)
//
#include <hip/hip_runtime.h>
#include <hip/hip_bf16.h>
#include <stdint.h>

static constexpr int kL  = 5;
static constexpr int kNH = 4;
static constexpr int kP  = 4;
static constexpr int kE  = 256;
static constexpr int kC  = 256;
static constexpr int kH  = 128;
static constexpr int kW  = 128;
static constexpr int kNQ = kH * kW;          // 16384
static constexpr int kNL = 6;
static constexpr int kFF = 2 * kE;           // 512
static constexpr int kCOMB = 240;            // 160 off + 80 aw (stored ld 256)

typedef short bf16x8 __attribute__((ext_vector_type(8)));
typedef float f32x4 __attribute__((ext_vector_type(4)));

__device__ __forceinline__ short f2bf(float x) {
  union { float f; uint32_t u; } v; v.f = x;
  uint32_t r = v.u + 0x7fffu + ((v.u >> 16) & 1u);
  return (short)(r >> 16);
}
__device__ __forceinline__ uint32_t pack2(float a, float b) {
  return (uint32_t)(unsigned short)f2bf(a) | ((uint32_t)(unsigned short)f2bf(b) << 16);
}
__device__ __forceinline__ float bflo(uint32_t u) { return __uint_as_float(u << 16); }
__device__ __forceinline__ float bfhi(uint32_t u) { return __uint_as_float(u & 0xffff0000u); }
__device__ __forceinline__ float bf2f(unsigned short u) {
  return __uint_as_float((uint32_t)u << 16);
}

__device__ __forceinline__ void gl_lds16(const void* g, void* l) {
  __builtin_amdgcn_global_load_lds(
      (const __attribute__((address_space(1))) void*)g,
      (__attribute__((address_space(3))) void*)l, 16, 0, 0);
}

// ---------------------------------------------------------------------------
// LDS-staged bf16 MFMA GEMM, BN=256 per x-block. Waves WRxWC (WR=4/WC).
// Wave tile: (MT*16 rows) x (NT*16 cols), MT=BM/(16*WR), NT=16/WC.
// LDS tiles are CHUNK-MAJOR: tile t occupies 512 shorts laid out as
// [kchunk(4)][row(16)][8 shorts]. Staged with srow=lane&15, kch=lane>>4
// (dest = base + lane*16B is exactly that layout); fragment reads at
// tile*512 + fq*128 + fr*8 -> dword-bank = fr*4 mod 32 -> 2-way (free),
// vs the old row-major layout's 8-way conflict (3.3M SQ_LDS_BANK_CONFLICT).
// MODE 0: bias (+relu) -> Cf and/or Cb
// MODE 1: x=acc+bias+resid; y=LN(x)*lng+lnb -> Cf fp32 [+Cb bf16] [+qp bf16]
// MODE 2: v=acc+bias -> Cf fp32, qp = bf16(v+pos)
// ---------------------------------------------------------------------------
template <int BM, int WC, int MODE>
__global__ __launch_bounds__(256) void gemm2_kernel(
    const short* __restrict__ A, long sAb, int lda,
    const short* __restrict__ BT, int ldbt, int Kb, int nbatch,
    const float* __restrict__ bias,
    float* Cf, short* __restrict__ Cb, int ldc, int relu,
    const float* resid, const float* __restrict__ lng,
    const float* __restrict__ lnb, short* __restrict__ qp,
    const float* __restrict__ pos_row, const float* __restrict__ pos_col) {
  constexpr int WR = 4 / WC;
  constexpr int MT = BM / (16 * WR);
  constexpr int NT = 16 / WC;
  constexpr int CW = 256 / WC;         // cols per wave
  constexpr int AI = BM / 16;          // A staging insts
  __shared__ short As[BM * 32];
  __shared__ short Bs[256 * 32];
  __shared__ float2 lnpart[(MODE == 1) ? BM : 1][WC];
  const int tid = threadIdx.x;
  const int wave = tid >> 6, lane = tid & 63;
  const int wy = wave / WC, wx = wave % WC;
  const long row0 = (long)blockIdx.y * BM;
  const int col0 = blockIdx.x * 256;
  const int srow = lane & 15;          // chunk-major staging: row
  const int skof = (lane >> 4) * 8;    // chunk-major staging: k-chunk
  const int fr = lane & 15, fq = lane >> 4;
  f32x4 acc[MT][NT] = {};
  for (int bb = 0; bb < nbatch; ++bb) {
    const short* Ab = A + (long)bb * sAb + row0 * lda;
    const short* Bb = BT + (long)col0 * ldbt + (long)bb * Kb;
    for (int k0 = 0; k0 < Kb; k0 += 32) {
      __syncthreads();
      for (int t = wave; t < AI + 16; t += 4) {
        if (t < AI)
          gl_lds16(Ab + (long)(t * 16 + srow) * lda + k0 + skof, &As[t * 512]);
        else {
          int u = t - AI;
          gl_lds16(Bb + (long)(u * 16 + srow) * ldbt + k0 + skof, &Bs[u * 512]);
        }
      }
      __syncthreads();
      bf16x8 af[MT], bfv[NT];
#pragma unroll
      for (int t = 0; t < MT; ++t)
        af[t] = *(const bf16x8*)&As[(wy * MT + t) * 512 + fq * 128 + fr * 8];
#pragma unroll
      for (int t = 0; t < NT; ++t)
        bfv[t] = *(const bf16x8*)&Bs[(wx * (CW / 16) + t) * 512 + fq * 128 + fr * 8];
#pragma unroll
      for (int mt = 0; mt < MT; ++mt)
#pragma unroll
        for (int nt = 0; nt < NT; ++nt)
          acc[mt][nt] = __builtin_amdgcn_mfma_f32_16x16x32_bf16(
              af[mt], bfv[nt], acc[mt][nt], 0, 0, 0);
    }
  }
  const int colb = col0 + wx * CW + fr;            // + nt*16
  const long rowb = row0 + wy * MT * 16 + fq * 4;  // + mt*16 + rr

  if (MODE == 0) {
#pragma unroll
    for (int mt = 0; mt < MT; ++mt)
#pragma unroll
      for (int rr = 0; rr < 4; ++rr) {
        long row = rowb + mt * 16 + rr;
#pragma unroll
        for (int nt = 0; nt < NT; ++nt) {
          int col = colb + nt * 16;
          float v = acc[mt][nt][rr] + bias[col];
          if (relu) v = fmaxf(v, 0.f);
          if (Cf) Cf[row * ldc + col] = v;
          if (Cb) Cb[row * ldc + col] = f2bf(v);
        }
      }
  } else if (MODE == 2) {
#pragma unroll
    for (int mt = 0; mt < MT; ++mt)
#pragma unroll
      for (int rr = 0; rr < 4; ++rr) {
        long row = rowb + mt * 16 + rr;
        int wpos = (int)row & (kW - 1), hpos = (int)row >> 7;
#pragma unroll
        for (int nt = 0; nt < NT; ++nt) {
          int col = colb + nt * 16;
          float v = acc[mt][nt][rr] + bias[col];
          Cf[row * 256 + col] = v;
          float pv = (col < 128) ? pos_col[wpos * 128 + col]
                                 : pos_row[hpos * 128 + (col - 128)];
          qp[row * 256 + col] = f2bf(v + pv);
        }
      }
  } else {
#pragma unroll
    for (int mt = 0; mt < MT; ++mt)
#pragma unroll
      for (int rr = 0; rr < 4; ++rr) {
        long row = rowb + mt * 16 + rr;
        float s = 0.f, s2 = 0.f;
#pragma unroll
        for (int nt = 0; nt < NT; ++nt) {
          int col = colb + nt * 16;
          float v = acc[mt][nt][rr] + bias[col] + resid[row * 256 + col];
          acc[mt][nt][rr] = v;
          s += v; s2 += v * v;
        }
#pragma unroll
        for (int o = 8; o > 0; o >>= 1) {
          s += __shfl_xor(s, o);
          s2 += __shfl_xor(s2, o);
        }
        if (fr == 0) {
          int rl = wy * MT * 16 + mt * 16 + fq * 4 + rr;
          lnpart[rl][wx] = make_float2(s, s2);
        }
      }
    __syncthreads();
#pragma unroll
    for (int mt = 0; mt < MT; ++mt)
#pragma unroll
      for (int rr = 0; rr < 4; ++rr) {
        int rl = wy * MT * 16 + mt * 16 + fq * 4 + rr;
        long row = rowb + mt * 16 + rr;
        float s = 0.f, s2 = 0.f;
#pragma unroll
        for (int c = 0; c < WC; ++c) {
          s += lnpart[rl][c].x; s2 += lnpart[rl][c].y;
        }
        float m = s * (1.f / 256);
        float var = s2 * (1.f / 256) - m * m;
        float rs = rsqrtf(var + 1e-5f);
        int wpos = (int)row & (kW - 1), hpos = (int)row >> 7;
#pragma unroll
        for (int nt = 0; nt < NT; ++nt) {
          int col = colb + nt * 16;
          float y = (acc[mt][nt][rr] - m) * rs * lng[col] + lnb[col];
          Cf[row * 256 + col] = y;
          if (Cb) Cb[row * 256 + col] = f2bf(y);
          if (qp) {
            float pv = (col < 128) ? pos_col[wpos * 128 + col]
                                   : pos_row[hpos * 128 + (col - 128)];
            qp[row * 256 + col] = f2bf(y + pv);
          }
        }
      }
  }
}

// ---------------------------------------------------------------------------
// weight convert+transpose: in fp32 [Z,K,N] -> out bf16 [Z,N,K]
__global__ __launch_bounds__(256) void wt_convert_kernel(
    const float* __restrict__ in, short* __restrict__ out, int K, int N) {
  long idx = (long)blockIdx.x * 256 + threadIdx.x;
  int z = blockIdx.y;
  int n = (int)(idx / K);
  int k = (int)(idx - (long)n * K);
  out[(long)z * N * K + idx] = f2bf(in[(long)z * K * N + (long)k * N + n]);
}

// off_w + aw_w -> combT bf16 [Z, 256 rows(n), 256(k)] + comb bias
__global__ __launch_bounds__(256) void comb_convert_kernel(
    const float* __restrict__ off_w, const float* __restrict__ aw_w,
    const float* __restrict__ off_b, const float* __restrict__ aw_b,
    short* __restrict__ combT, float* __restrict__ comb_bias) {
  int idx = blockIdx.x * 256 + threadIdx.x;
  int z = blockIdx.y;
  int n = idx >> 8, k = idx & 255;
  float v = 0.f;
  if (n < 160) v = off_w[((long)z * 256 + k) * 160 + n];
  else if (n < kCOMB) v = aw_w[((long)z * 256 + k) * 80 + (n - 160)];
  combT[(long)z * 65536 + idx] = f2bf(v);
  if (k == 0)
    comb_bias[z * 256 + n] =
        (n < 160) ? off_b[z * 160 + n]
                  : (n < kCOMB ? aw_b[z * 80 + (n - 160)] : 0.f);
}

// ---------------------------------------------------------------------------
// LN over channels of feat [L, C, nq]: stats
__global__ __launch_bounds__(256) void ln_stats_kernel(
    const float* __restrict__ feat, float* __restrict__ mean_out,
    float* __restrict__ rstd_out) {
  int i = blockIdx.x * 256 + threadIdx.x;
  int l = i >> 14;
  int n = i & (kNQ - 1);
  const float* base = feat + (long)l * kC * kNQ + n;
  float s = 0.f, s2 = 0.f;
  for (int c = 0; c < kC; ++c) {
    float v = base[(long)c * kNQ];
    s += v; s2 += v * v;
  }
  float m = s * (1.f / kC);
  float var = s2 * (1.f / kC) - m * m;
  mean_out[i] = m;
  rstd_out[i] = rsqrtf(var + 1e-5f);
}

// LN apply + transpose -> f bf16 [L, nq, C]
__global__ __launch_bounds__(256) void ln_apply_kernel(
    const float* __restrict__ feat, const float* __restrict__ mean_in,
    const float* __restrict__ rstd_in, const float* __restrict__ g,
    const float* __restrict__ b, short* __restrict__ f) {
  __shared__ float tile[32][33];
  int l  = blockIdx.z;
  int cb = blockIdx.x * 32, nb = blockIdx.y * 32;
  int tx = threadIdx.x & 31;
  int ty = threadIdx.x >> 5;
#pragma unroll
  for (int j = 0; j < 4; ++j) {
    int c = ty + j * 8;
    tile[c][tx] = feat[((long)(l * kC + cb + c)) * kNQ + nb + tx];
  }
  __syncthreads();
#pragma unroll
  for (int j = 0; j < 4; ++j) {
    int nl = ty + j * 8;
    int n  = nb + nl;
    float m  = mean_in[l * kNQ + n];
    float rs = rstd_in[l * kNQ + n];
    int c = cb + tx;
    float v = (tile[tx][nl] - m) * rs * g[l * kC + c] + b[l * kC + c];
    f[((long)l * kNQ + n) * kC + c] = f2bf(v);
  }
}

// ---------------------------------------------------------------------------
// Deformable sampling: wave handles 2 queries (32 lanes each), all 4 heads.
// comb is bf16 [nq][256]: offsets at h*40+lp*2, scores at 160+h*20+lp.
__global__ __launch_bounds__(256) void sample_kernel(
    const unsigned short* __restrict__ comb, const short* __restrict__ val,
    short* __restrict__ accb) {
  __shared__ float2 ic[4][2][4][85];
  int wv = threadIdx.x >> 6;
  int lane = threadIdx.x & 63;
  int half = lane >> 5;
  int hl = lane & 31;
  int n = blockIdx.x * 8 + wv * 2 + half;
  int wq = n & (kW - 1);
  int hq = n >> 7;
  const unsigned short* cb = comb + (long)n * 256;
#pragma unroll
  for (int h = 0; h < 4; ++h) {
    float raw = (hl < 20) ? bf2f(cb[160 + h * 20 + hl]) : -1e30f;
    float mx = raw;
#pragma unroll
    for (int o = 16; o > 0; o >>= 1) mx = fmaxf(mx, __shfl_xor(mx, o));
    float ev = (hl < 20) ? __expf(raw - mx) : 0.f;
    float se = ev;
#pragma unroll
    for (int o = 16; o > 0; o >>= 1) se += __shfl_xor(se, o);
    if (hl < 20) {
      float awv = ev / se;
      int l = hl >> 2;
      float ox = bf2f(cb[h * 40 + hl * 2 + 0]);
      float oy = bf2f(cb[h * 40 + hl * 2 + 1]);
      float x = (float)wq + ox;
      float y = (float)hq + oy;
      float x0f = floorf(x), y0f = floorf(y);
      float fx = x - x0f, fy = y - y0f;
      int x0 = (int)x0f, y0 = (int)y0f;
#pragma unroll
      for (int c = 0; c < 4; ++c) {
        int dx = c & 1, dy = c >> 1;
        int ix = x0 + dx, iy = y0 + dy;
        float wgt = (dx ? fx : 1.f - fx) * (dy ? fy : 1.f - fy);
        bool valid = (ix >= 0 && ix < kW && iy >= 0 && iy < kH);
        int cix = min(max(ix, 0), kW - 1);
        int ciy = min(max(iy, 0), kH - 1);
        int sidx = ciy * kW + cix;
        int byteoff = (l * kNQ + sidx) * (kE * 2);
        float coef = valid ? awv * wgt : 0.f;
        ic[wv][half][h][hl * 4 + c] = make_float2(__int_as_float(byteoff), coef);
      }
    }
  }
  __syncthreads();
  int h2 = (lane >> 3) & 3;
  int ch8 = (lane & 7) * 8;
  const char* vb = (const char*)val + (h2 * 64 + ch8) * 2;
  const float2* icp = &ic[wv][half][h2][0];
  float a0 = 0.f, a1 = 0.f, a2 = 0.f, a3 = 0.f;
  float a4 = 0.f, a5 = 0.f, a6 = 0.f, a7 = 0.f;
#pragma unroll 4
  for (int j = 0; j < 80; ++j) {
    float2 oc = icp[j];
    int off = __float_as_int(oc.x);
    uint4 u = *(const uint4*)(vb + off);
    float cf = oc.y;
    a0 += cf * bflo(u.x); a1 += cf * bfhi(u.x);
    a2 += cf * bflo(u.y); a3 += cf * bfhi(u.y);
    a4 += cf * bflo(u.z); a5 += cf * bfhi(u.z);
    a6 += cf * bflo(u.w); a7 += cf * bfhi(u.w);
  }
  uint4 o;
  o.x = pack2(a0, a1); o.y = pack2(a2, a3);
  o.z = pack2(a4, a5); o.w = pack2(a6, a7);
  *(uint4*)(accb + (long)n * kE + h2 * 64 + ch8) = o;
}

// final transpose: out[e, n] = q[n, e]
__global__ __launch_bounds__(256) void transpose_kernel(
    const float* __restrict__ q, float* __restrict__ out) {
  __shared__ float t[32][33];
  int eb = blockIdx.x * 32, nb = blockIdx.y * 32;
  int tx = threadIdx.x & 31, ty = threadIdx.x >> 5;
#pragma unroll
  for (int j = 0; j < 4; ++j)
    t[ty + j * 8][tx] = q[(long)(nb + ty + j * 8) * kE + eb + tx];
  __syncthreads();
#pragma unroll
  for (int j = 0; j < 4; ++j)
    out[(long)(eb + ty + j * 8) * kNQ + nb + tx] = t[tx][ty + j * 8];
}

extern "C" void kernel_launch(void* const* d_in, const int* in_sizes, int n_in,
                              void* d_out, int out_size, void* d_ws,
                              size_t ws_size, hipStream_t stream) {
  const float* feat    = (const float*)d_in[0];
  const float* norm0_g = (const float*)d_in[1];
  const float* norm0_b = (const float*)d_in[2];
  const float* in_w    = (const float*)d_in[3];
  const float* in_b    = (const float*)d_in[4];
  const float* pos_row = (const float*)d_in[5];
  const float* pos_col = (const float*)d_in[6];
  const float* off_w   = (const float*)d_in[7];
  const float* off_b   = (const float*)d_in[8];
  const float* aw_w    = (const float*)d_in[9];
  const float* aw_b    = (const float*)d_in[10];
  const float* val_w   = (const float*)d_in[11];
  const float* val_b   = (const float*)d_in[12];
  const float* out_w   = (const float*)d_in[13];
  const float* out_b   = (const float*)d_in[14];
  const float* ln1_g   = (const float*)d_in[15];
  const float* ln1_b   = (const float*)d_in[16];
  const float* ln2_g   = (const float*)d_in[17];
  const float* ln2_b   = (const float*)d_in[18];
  const float* ffn_w1  = (const float*)d_in[19];
  const float* ffn_b1  = (const float*)d_in[20];
  const float* ffn_w2  = (const float*)d_in[21];
  const float* ffn_b2  = (const float*)d_in[22];

  char* p = (char*)d_ws;
  auto alloc = [&](size_t bytes) -> char* {
    char* r = p;
    p += (bytes + 255) & ~(size_t)255;
    return r;
  };
  short* f_bf    = (short*)alloc((size_t)kL * kNQ * kC * 2);
  short* val_bf  = (short*)alloc((size_t)kL * kNQ * kE * 2);
  float* q       = (float*)alloc((size_t)kNQ * kE * 4);
  short* qbf     = (short*)alloc((size_t)kNQ * kE * 2);
  short* qp_bf   = (short*)alloc((size_t)kNQ * kE * 2);
  short* accb    = (short*)alloc((size_t)kNQ * kE * 2);
  short* hid_bf  = (short*)alloc((size_t)kNQ * kFF * 2);
  short* comb_bf = (short*)alloc((size_t)kNQ * 256 * 2);
  float* comb_b  = (float*)alloc((size_t)kNL * 256 * 4);
  float* meanb   = (float*)alloc((size_t)kL * kNQ * 4);
  float* rstdb   = (float*)alloc((size_t)kL * kNQ * 4);
  short* inT     = (short*)alloc((size_t)256 * 1280 * 2);
  short* valT    = (short*)alloc((size_t)kNL * 256 * 256 * 2);
  short* outT    = (short*)alloc((size_t)kNL * 256 * 256 * 2);
  short* ffn1T   = (short*)alloc((size_t)kNL * 512 * 256 * 2);
  short* ffn2T   = (short*)alloc((size_t)kNL * 256 * 512 * 2);
  short* combT   = (short*)alloc((size_t)kNL * 256 * 256 * 2);

  // weight conversions (bf16, transposed to [N,K])
  wt_convert_kernel<<<dim3(1280, 1), 256, 0, stream>>>(in_w, inT, 1280, 256);
  wt_convert_kernel<<<dim3(256, kNL), 256, 0, stream>>>(val_w, valT, 256, 256);
  wt_convert_kernel<<<dim3(256, kNL), 256, 0, stream>>>(out_w, outT, 256, 256);
  wt_convert_kernel<<<dim3(512, kNL), 256, 0, stream>>>(ffn_w1, ffn1T, 256, 512);
  wt_convert_kernel<<<dim3(512, kNL), 256, 0, stream>>>(ffn_w2, ffn2T, 512, 256);
  comb_convert_kernel<<<dim3(256, kNL), 256, 0, stream>>>(off_w, aw_w, off_b,
                                                          aw_b, combT, comb_b);

  // feature LN -> f bf16
  ln_stats_kernel<<<kL * kNQ / 256, 256, 0, stream>>>(feat, meanb, rstdb);
  ln_apply_kernel<<<dim3(kC / 32, kNQ / 32, kL), 256, 0, stream>>>(
      feat, meanb, rstdb, norm0_g, norm0_b, f_bf);

  // input proj + pos-add epilogue: q fp32, qp_bf bf16
  gemm2_kernel<16, 4, 2><<<dim3(1, kNQ / 16), 256, 0, stream>>>(
      f_bf, (long)kNQ * kC, kC, inT, 1280, 256, kL, in_b,
      q, nullptr, 256, 0, nullptr, nullptr, nullptr, qp_bf, pos_row, pos_col);

  for (int i = 0; i < kNL; ++i) {
    const short* combT_i = combT + (long)i * 256 * 256;
    const short* valT_i  = valT + (long)i * 256 * 256;
    const short* outT_i  = outT + (long)i * 256 * 256;
    const short* f1T_i   = ffn1T + (long)i * 512 * 256;
    const short* f2T_i   = ffn2T + (long)i * 256 * 512;

    // off+aw scores -> comb bf16 [nq][256]
    gemm2_kernel<16, 4, 0><<<dim3(1, kNQ / 16), 256, 0, stream>>>(
        qp_bf, 0, kE, combT_i, 256, 256, 1, comb_b + i * 256,
        nullptr, comb_bf, 256, 0, nullptr, nullptr, nullptr, nullptr,
        nullptr, nullptr);
    // val = f @ val_w[i] (M = L*nq) -> bf16 (LDS-staged, BM=64)
    gemm2_kernel<64, 2, 0><<<dim3(1, kL * kNQ / 64), 256, 0, stream>>>(
        f_bf, 0, kC, valT_i, 256, 256, 1, val_b + (long)i * kE,
        nullptr, val_bf, kE, 0, nullptr, nullptr, nullptr, nullptr,
        nullptr, nullptr);
    // fused softmax + sampling
    sample_kernel<<<kNQ / 8, 256, 0, stream>>>((const unsigned short*)comb_bf,
                                               val_bf, accb);
    // out proj + residual + LN1 -> q fp32, qbf bf16
    gemm2_kernel<16, 4, 1><<<dim3(1, kNQ / 16), 256, 0, stream>>>(
        accb, 0, kE, outT_i, 256, 256, 1, out_b + (long)i * kE,
        q, qbf, 256, 0, q, ln1_g + (long)i * kE, ln1_b + (long)i * kE,
        nullptr, nullptr, nullptr);
    // FFN1 (N=512, relu) -> hid_bf (LDS-staged, BM=32)
    gemm2_kernel<32, 2, 0><<<dim3(2, kNQ / 32), 256, 0, stream>>>(
        qbf, 0, kE, f1T_i, 256, 256, 1, ffn_b1 + (long)i * kFF,
        nullptr, hid_bf, kFF, 1, nullptr, nullptr, nullptr, nullptr,
        nullptr, nullptr);
    // FFN2 (K=512) + residual + LN2 -> q fp32 (+ qp_bf for next layer)
    gemm2_kernel<16, 4, 1><<<dim3(1, kNQ / 16), 256, 0, stream>>>(
        hid_bf, 0, kFF, f2T_i, 512, 512, 1, ffn_b2 + (long)i * kE,
        q, nullptr, 256, 0, q, ln2_g + (long)i * kE, ln2_b + (long)i * kE,
        (i + 1 < kNL) ? qp_bf : nullptr, pos_row, pos_col);
  }

  transpose_kernel<<<dim3(kE / 32, kNQ / 32), 256, 0, stream>>>(q,
                                                                (float*)d_out);
}

// Round 10
// 1089.646 us; speedup vs baseline: 1.2923x; 1.2923x over previous
//
#include <hip/hip_runtime.h>
#include <hip/hip_bf16.h>
#include <stdint.h>

static constexpr int kL  = 5;
static constexpr int kNH = 4;
static constexpr int kP  = 4;
static constexpr int kE  = 256;
static constexpr int kC  = 256;
static constexpr int kH  = 128;
static constexpr int kW  = 128;
static constexpr int kNQ = kH * kW;          // 16384
static constexpr int kNL = 6;
static constexpr int kFF = 2 * kE;           // 512
static constexpr int kCOMB = 240;            // 160 off + 80 aw (stored ld 256)

typedef short bf16x8 __attribute__((ext_vector_type(8)));
typedef float f32x4 __attribute__((ext_vector_type(4)));

__device__ __forceinline__ short f2bf(float x) {
  union { float f; uint32_t u; } v; v.f = x;
  uint32_t r = v.u + 0x7fffu + ((v.u >> 16) & 1u);
  return (short)(r >> 16);
}
__device__ __forceinline__ uint32_t pack2(float a, float b) {
  return (uint32_t)(unsigned short)f2bf(a) | ((uint32_t)(unsigned short)f2bf(b) << 16);
}
__device__ __forceinline__ float bflo(uint32_t u) { return __uint_as_float(u << 16); }
__device__ __forceinline__ float bfhi(uint32_t u) { return __uint_as_float(u & 0xffff0000u); }
__device__ __forceinline__ float bf2f(unsigned short u) {
  return __uint_as_float((uint32_t)u << 16);
}

__device__ __forceinline__ void gl_lds16(const void* g, void* l) {
  __builtin_amdgcn_global_load_lds(
      (const __attribute__((address_space(1))) void*)g,
      (__attribute__((address_space(3))) void*)l, 16, 0, 0);
}

// ---------------------------------------------------------------------------
// LDS-staged bf16 MFMA GEMM, BN=256 per x-block. Waves WRxWC (WR=4/WC).
// Wave tile: (MT*16 rows) x (NT*16 cols), MT=BM/(16*WR), NT=16/WC.
//
// XOR-SWIZZLED tiles (lesson from R7/R9 A-B test):
//  - staging keeps R7's lane->global quad pattern (lanes 4r..4r+3 read row
//    r's 64B segment -> 1 cache line per quad, coalescer-friendly), but each
//    lane reads k-chunk (lane&3)^(row&3) of its row. LDS unit u holds
//    (row=u>>2, kc=(u&3)^((u>>2)&3)).
//  - fragment read for lane (fr,fq): u = fr*4 + (fq^(fr&3)) -> u mod 8
//    uniform over 8 four-bank groups -> 2-way aliasing = free.
//    (R7 row-major: 8-way conflict, 3.3M SQ_LDS_BANK_CONFLICT; R9
//    chunk-major: conflict-free but 4x staging transactions -> slower.)
//
// MODE 0: bias (+relu) -> Cf and/or Cb
// MODE 1: x=acc+bias+resid; y=LN(x)*lng+lnb -> Cf fp32 [+Cb bf16] [+qp bf16]
// MODE 2: v=acc+bias -> Cf fp32, qp = bf16(v+pos)
// ---------------------------------------------------------------------------
template <int BM, int WC, int MODE>
__global__ __launch_bounds__(256) void gemm2_kernel(
    const short* __restrict__ A, long sAb, int lda,
    const short* __restrict__ BT, int ldbt, int Kb, int nbatch,
    const float* __restrict__ bias,
    float* Cf, short* __restrict__ Cb, int ldc, int relu,
    const float* resid, const float* __restrict__ lng,
    const float* __restrict__ lnb, short* __restrict__ qp,
    const float* __restrict__ pos_row, const float* __restrict__ pos_col) {
  constexpr int WR = 4 / WC;
  constexpr int MT = BM / (16 * WR);
  constexpr int NT = 16 / WC;
  constexpr int CW = 256 / WC;         // cols per wave
  constexpr int AI = BM / 16;          // A staging insts
  __shared__ short As[BM * 32];
  __shared__ short Bs[256 * 32];
  __shared__ float2 lnpart[(MODE == 1) ? BM : 1][WC];
  const int tid = threadIdx.x;
  const int wave = tid >> 6, lane = tid & 63;
  const int wy = wave / WC, wx = wave % WC;
  const long row0 = (long)blockIdx.y * BM;
  const int col0 = blockIdx.x * 256;
  const int srow = lane >> 2;                        // R7 quad pattern
  const int skof = ((lane & 3) ^ (srow & 3)) * 8;    // XOR-swizzled chunk
  const int fr = lane & 15, fq = lane >> 4;
  const int ua = (fr * 4 + (fq ^ (fr & 3))) * 8;     // fragment read offset
  f32x4 acc[MT][NT] = {};
  for (int bb = 0; bb < nbatch; ++bb) {
    const short* Ab = A + (long)bb * sAb + row0 * lda;
    const short* Bb = BT + (long)col0 * ldbt + (long)bb * Kb;
    for (int k0 = 0; k0 < Kb; k0 += 32) {
      __syncthreads();
      for (int t = wave; t < AI + 16; t += 4) {
        if (t < AI)
          gl_lds16(Ab + (long)(t * 16 + srow) * lda + k0 + skof, &As[t * 512]);
        else {
          int u = t - AI;
          gl_lds16(Bb + (long)(u * 16 + srow) * ldbt + k0 + skof, &Bs[u * 512]);
        }
      }
      __syncthreads();
      bf16x8 af[MT], bfv[NT];
#pragma unroll
      for (int t = 0; t < MT; ++t)
        af[t] = *(const bf16x8*)&As[(wy * MT + t) * 512 + ua];
#pragma unroll
      for (int t = 0; t < NT; ++t)
        bfv[t] = *(const bf16x8*)&Bs[(wx * (CW / 16) + t) * 512 + ua];
#pragma unroll
      for (int mt = 0; mt < MT; ++mt)
#pragma unroll
        for (int nt = 0; nt < NT; ++nt)
          acc[mt][nt] = __builtin_amdgcn_mfma_f32_16x16x32_bf16(
              af[mt], bfv[nt], acc[mt][nt], 0, 0, 0);
    }
  }
  const int colb = col0 + wx * CW + fr;            // + nt*16
  const long rowb = row0 + wy * MT * 16 + fq * 4;  // + mt*16 + rr

  if (MODE == 0) {
#pragma unroll
    for (int mt = 0; mt < MT; ++mt)
#pragma unroll
      for (int rr = 0; rr < 4; ++rr) {
        long row = rowb + mt * 16 + rr;
#pragma unroll
        for (int nt = 0; nt < NT; ++nt) {
          int col = colb + nt * 16;
          float v = acc[mt][nt][rr] + bias[col];
          if (relu) v = fmaxf(v, 0.f);
          if (Cf) Cf[row * ldc + col] = v;
          if (Cb) Cb[row * ldc + col] = f2bf(v);
        }
      }
  } else if (MODE == 2) {
#pragma unroll
    for (int mt = 0; mt < MT; ++mt)
#pragma unroll
      for (int rr = 0; rr < 4; ++rr) {
        long row = rowb + mt * 16 + rr;
        int wpos = (int)row & (kW - 1), hpos = (int)row >> 7;
#pragma unroll
        for (int nt = 0; nt < NT; ++nt) {
          int col = colb + nt * 16;
          float v = acc[mt][nt][rr] + bias[col];
          Cf[row * 256 + col] = v;
          float pv = (col < 128) ? pos_col[wpos * 128 + col]
                                 : pos_row[hpos * 128 + (col - 128)];
          qp[row * 256 + col] = f2bf(v + pv);
        }
      }
  } else {
#pragma unroll
    for (int mt = 0; mt < MT; ++mt)
#pragma unroll
      for (int rr = 0; rr < 4; ++rr) {
        long row = rowb + mt * 16 + rr;
        float s = 0.f, s2 = 0.f;
#pragma unroll
        for (int nt = 0; nt < NT; ++nt) {
          int col = colb + nt * 16;
          float v = acc[mt][nt][rr] + bias[col] + resid[row * 256 + col];
          acc[mt][nt][rr] = v;
          s += v; s2 += v * v;
        }
#pragma unroll
        for (int o = 8; o > 0; o >>= 1) {
          s += __shfl_xor(s, o);
          s2 += __shfl_xor(s2, o);
        }
        if (fr == 0) {
          int rl = wy * MT * 16 + mt * 16 + fq * 4 + rr;
          lnpart[rl][wx] = make_float2(s, s2);
        }
      }
    __syncthreads();
#pragma unroll
    for (int mt = 0; mt < MT; ++mt)
#pragma unroll
      for (int rr = 0; rr < 4; ++rr) {
        int rl = wy * MT * 16 + mt * 16 + fq * 4 + rr;
        long row = rowb + mt * 16 + rr;
        float s = 0.f, s2 = 0.f;
#pragma unroll
        for (int c = 0; c < WC; ++c) {
          s += lnpart[rl][c].x; s2 += lnpart[rl][c].y;
        }
        float m = s * (1.f / 256);
        float var = s2 * (1.f / 256) - m * m;
        float rs = rsqrtf(var + 1e-5f);
        int wpos = (int)row & (kW - 1), hpos = (int)row >> 7;
#pragma unroll
        for (int nt = 0; nt < NT; ++nt) {
          int col = colb + nt * 16;
          float y = (acc[mt][nt][rr] - m) * rs * lng[col] + lnb[col];
          Cf[row * 256 + col] = y;
          if (Cb) Cb[row * 256 + col] = f2bf(y);
          if (qp) {
            float pv = (col < 128) ? pos_col[wpos * 128 + col]
                                   : pos_row[hpos * 128 + (col - 128)];
            qp[row * 256 + col] = f2bf(y + pv);
          }
        }
      }
  }
}

// ---------------------------------------------------------------------------
// weight convert+transpose: in fp32 [Z,K,N] -> out bf16 [Z,N,K]
__global__ __launch_bounds__(256) void wt_convert_kernel(
    const float* __restrict__ in, short* __restrict__ out, int K, int N) {
  long idx = (long)blockIdx.x * 256 + threadIdx.x;
  int z = blockIdx.y;
  int n = (int)(idx / K);
  int k = (int)(idx - (long)n * K);
  out[(long)z * N * K + idx] = f2bf(in[(long)z * K * N + (long)k * N + n]);
}

// off_w + aw_w -> combT bf16 [Z, 256 rows(n), 256(k)] + comb bias
__global__ __launch_bounds__(256) void comb_convert_kernel(
    const float* __restrict__ off_w, const float* __restrict__ aw_w,
    const float* __restrict__ off_b, const float* __restrict__ aw_b,
    short* __restrict__ combT, float* __restrict__ comb_bias) {
  int idx = blockIdx.x * 256 + threadIdx.x;
  int z = blockIdx.y;
  int n = idx >> 8, k = idx & 255;
  float v = 0.f;
  if (n < 160) v = off_w[((long)z * 256 + k) * 160 + n];
  else if (n < kCOMB) v = aw_w[((long)z * 256 + k) * 80 + (n - 160)];
  combT[(long)z * 65536 + idx] = f2bf(v);
  if (k == 0)
    comb_bias[z * 256 + n] =
        (n < 160) ? off_b[z * 160 + n]
                  : (n < kCOMB ? aw_b[z * 80 + (n - 160)] : 0.f);
}

// ---------------------------------------------------------------------------
// LN over channels of feat [L, C, nq]: stats
__global__ __launch_bounds__(256) void ln_stats_kernel(
    const float* __restrict__ feat, float* __restrict__ mean_out,
    float* __restrict__ rstd_out) {
  int i = blockIdx.x * 256 + threadIdx.x;
  int l = i >> 14;
  int n = i & (kNQ - 1);
  const float* base = feat + (long)l * kC * kNQ + n;
  float s = 0.f, s2 = 0.f;
  for (int c = 0; c < kC; ++c) {
    float v = base[(long)c * kNQ];
    s += v; s2 += v * v;
  }
  float m = s * (1.f / kC);
  float var = s2 * (1.f / kC) - m * m;
  mean_out[i] = m;
  rstd_out[i] = rsqrtf(var + 1e-5f);
}

// LN apply + transpose -> f bf16 [L, nq, C]
__global__ __launch_bounds__(256) void ln_apply_kernel(
    const float* __restrict__ feat, const float* __restrict__ mean_in,
    const float* __restrict__ rstd_in, const float* __restrict__ g,
    const float* __restrict__ b, short* __restrict__ f) {
  __shared__ float tile[32][33];
  int l  = blockIdx.z;
  int cb = blockIdx.x * 32, nb = blockIdx.y * 32;
  int tx = threadIdx.x & 31;
  int ty = threadIdx.x >> 5;
#pragma unroll
  for (int j = 0; j < 4; ++j) {
    int c = ty + j * 8;
    tile[c][tx] = feat[((long)(l * kC + cb + c)) * kNQ + nb + tx];
  }
  __syncthreads();
#pragma unroll
  for (int j = 0; j < 4; ++j) {
    int nl = ty + j * 8;
    int n  = nb + nl;
    float m  = mean_in[l * kNQ + n];
    float rs = rstd_in[l * kNQ + n];
    int c = cb + tx;
    float v = (tile[tx][nl] - m) * rs * g[l * kC + c] + b[l * kC + c];
    f[((long)l * kNQ + n) * kC + c] = f2bf(v);
  }
}

// ---------------------------------------------------------------------------
// Deformable sampling: wave handles 2 queries (32 lanes each), all 4 heads.
// comb is bf16 [nq][256]: offsets at h*40+lp*2, scores at 160+h*20+lp.
__global__ __launch_bounds__(256) void sample_kernel(
    const unsigned short* __restrict__ comb, const short* __restrict__ val,
    short* __restrict__ accb) {
  __shared__ float2 ic[4][2][4][85];
  int wv = threadIdx.x >> 6;
  int lane = threadIdx.x & 63;
  int half = lane >> 5;
  int hl = lane & 31;
  int n = blockIdx.x * 8 + wv * 2 + half;
  int wq = n & (kW - 1);
  int hq = n >> 7;
  const unsigned short* cb = comb + (long)n * 256;
#pragma unroll
  for (int h = 0; h < 4; ++h) {
    float raw = (hl < 20) ? bf2f(cb[160 + h * 20 + hl]) : -1e30f;
    float mx = raw;
#pragma unroll
    for (int o = 16; o > 0; o >>= 1) mx = fmaxf(mx, __shfl_xor(mx, o));
    float ev = (hl < 20) ? __expf(raw - mx) : 0.f;
    float se = ev;
#pragma unroll
    for (int o = 16; o > 0; o >>= 1) se += __shfl_xor(se, o);
    if (hl < 20) {
      float awv = ev / se;
      int l = hl >> 2;
      float ox = bf2f(cb[h * 40 + hl * 2 + 0]);
      float oy = bf2f(cb[h * 40 + hl * 2 + 1]);
      float x = (float)wq + ox;
      float y = (float)hq + oy;
      float x0f = floorf(x), y0f = floorf(y);
      float fx = x - x0f, fy = y - y0f;
      int x0 = (int)x0f, y0 = (int)y0f;
#pragma unroll
      for (int c = 0; c < 4; ++c) {
        int dx = c & 1, dy = c >> 1;
        int ix = x0 + dx, iy = y0 + dy;
        float wgt = (dx ? fx : 1.f - fx) * (dy ? fy : 1.f - fy);
        bool valid = (ix >= 0 && ix < kW && iy >= 0 && iy < kH);
        int cix = min(max(ix, 0), kW - 1);
        int ciy = min(max(iy, 0), kH - 1);
        int sidx = ciy * kW + cix;
        int byteoff = (l * kNQ + sidx) * (kE * 2);
        float coef = valid ? awv * wgt : 0.f;
        ic[wv][half][h][hl * 4 + c] = make_float2(__int_as_float(byteoff), coef);
      }
    }
  }
  __syncthreads();
  int h2 = (lane >> 3) & 3;
  int ch8 = (lane & 7) * 8;
  const char* vb = (const char*)val + (h2 * 64 + ch8) * 2;
  const float2* icp = &ic[wv][half][h2][0];
  float a0 = 0.f, a1 = 0.f, a2 = 0.f, a3 = 0.f;
  float a4 = 0.f, a5 = 0.f, a6 = 0.f, a7 = 0.f;
#pragma unroll 4
  for (int j = 0; j < 80; ++j) {
    float2 oc = icp[j];
    int off = __float_as_int(oc.x);
    uint4 u = *(const uint4*)(vb + off);
    float cf = oc.y;
    a0 += cf * bflo(u.x); a1 += cf * bfhi(u.x);
    a2 += cf * bflo(u.y); a3 += cf * bfhi(u.y);
    a4 += cf * bflo(u.z); a5 += cf * bfhi(u.z);
    a6 += cf * bflo(u.w); a7 += cf * bfhi(u.w);
  }
  uint4 o;
  o.x = pack2(a0, a1); o.y = pack2(a2, a3);
  o.z = pack2(a4, a5); o.w = pack2(a6, a7);
  *(uint4*)(accb + (long)n * kE + h2 * 64 + ch8) = o;
}

// final transpose: out[e, n] = q[n, e]
__global__ __launch_bounds__(256) void transpose_kernel(
    const float* __restrict__ q, float* __restrict__ out) {
  __shared__ float t[32][33];
  int eb = blockIdx.x * 32, nb = blockIdx.y * 32;
  int tx = threadIdx.x & 31, ty = threadIdx.x >> 5;
#pragma unroll
  for (int j = 0; j < 4; ++j)
    t[ty + j * 8][tx] = q[(long)(nb + ty + j * 8) * kE + eb + tx];
  __syncthreads();
#pragma unroll
  for (int j = 0; j < 4; ++j)
    out[(long)(eb + ty + j * 8) * kNQ + nb + tx] = t[tx][ty + j * 8];
}

extern "C" void kernel_launch(void* const* d_in, const int* in_sizes, int n_in,
                              void* d_out, int out_size, void* d_ws,
                              size_t ws_size, hipStream_t stream) {
  const float* feat    = (const float*)d_in[0];
  const float* norm0_g = (const float*)d_in[1];
  const float* norm0_b = (const float*)d_in[2];
  const float* in_w    = (const float*)d_in[3];
  const float* in_b    = (const float*)d_in[4];
  const float* pos_row = (const float*)d_in[5];
  const float* pos_col = (const float*)d_in[6];
  const float* off_w   = (const float*)d_in[7];
  const float* off_b   = (const float*)d_in[8];
  const float* aw_w    = (const float*)d_in[9];
  const float* aw_b    = (const float*)d_in[10];
  const float* val_w   = (const float*)d_in[11];
  const float* val_b   = (const float*)d_in[12];
  const float* out_w   = (const float*)d_in[13];
  const float* out_b   = (const float*)d_in[14];
  const float* ln1_g   = (const float*)d_in[15];
  const float* ln1_b   = (const float*)d_in[16];
  const float* ln2_g   = (const float*)d_in[17];
  const float* ln2_b   = (const float*)d_in[18];
  const float* ffn_w1  = (const float*)d_in[19];
  const float* ffn_b1  = (const float*)d_in[20];
  const float* ffn_w2  = (const float*)d_in[21];
  const float* ffn_b2  = (const float*)d_in[22];

  char* p = (char*)d_ws;
  auto alloc = [&](size_t bytes) -> char* {
    char* r = p;
    p += (bytes + 255) & ~(size_t)255;
    return r;
  };
  short* f_bf    = (short*)alloc((size_t)kL * kNQ * kC * 2);
  short* val_bf  = (short*)alloc((size_t)kL * kNQ * kE * 2);
  float* q       = (float*)alloc((size_t)kNQ * kE * 4);
  short* qbf     = (short*)alloc((size_t)kNQ * kE * 2);
  short* qp_bf   = (short*)alloc((size_t)kNQ * kE * 2);
  short* accb    = (short*)alloc((size_t)kNQ * kE * 2);
  short* hid_bf  = (short*)alloc((size_t)kNQ * kFF * 2);
  short* comb_bf = (short*)alloc((size_t)kNQ * 256 * 2);
  float* comb_b  = (float*)alloc((size_t)kNL * 256 * 4);
  float* meanb   = (float*)alloc((size_t)kL * kNQ * 4);
  float* rstdb   = (float*)alloc((size_t)kL * kNQ * 4);
  short* inT     = (short*)alloc((size_t)256 * 1280 * 2);
  short* valT    = (short*)alloc((size_t)kNL * 256 * 256 * 2);
  short* outT    = (short*)alloc((size_t)kNL * 256 * 256 * 2);
  short* ffn1T   = (short*)alloc((size_t)kNL * 512 * 256 * 2);
  short* ffn2T   = (short*)alloc((size_t)kNL * 256 * 512 * 2);
  short* combT   = (short*)alloc((size_t)kNL * 256 * 256 * 2);

  // weight conversions (bf16, transposed to [N,K])
  wt_convert_kernel<<<dim3(1280, 1), 256, 0, stream>>>(in_w, inT, 1280, 256);
  wt_convert_kernel<<<dim3(256, kNL), 256, 0, stream>>>(val_w, valT, 256, 256);
  wt_convert_kernel<<<dim3(256, kNL), 256, 0, stream>>>(out_w, outT, 256, 256);
  wt_convert_kernel<<<dim3(512, kNL), 256, 0, stream>>>(ffn_w1, ffn1T, 256, 512);
  wt_convert_kernel<<<dim3(512, kNL), 256, 0, stream>>>(ffn_w2, ffn2T, 512, 256);
  comb_convert_kernel<<<dim3(256, kNL), 256, 0, stream>>>(off_w, aw_w, off_b,
                                                          aw_b, combT, comb_b);

  // feature LN -> f bf16
  ln_stats_kernel<<<kL * kNQ / 256, 256, 0, stream>>>(feat, meanb, rstdb);
  ln_apply_kernel<<<dim3(kC / 32, kNQ / 32, kL), 256, 0, stream>>>(
      feat, meanb, rstdb, norm0_g, norm0_b, f_bf);

  // input proj + pos-add epilogue: q fp32, qp_bf bf16
  gemm2_kernel<16, 4, 2><<<dim3(1, kNQ / 16), 256, 0, stream>>>(
      f_bf, (long)kNQ * kC, kC, inT, 1280, 256, kL, in_b,
      q, nullptr, 256, 0, nullptr, nullptr, nullptr, qp_bf, pos_row, pos_col);

  for (int i = 0; i < kNL; ++i) {
    const short* combT_i = combT + (long)i * 256 * 256;
    const short* valT_i  = valT + (long)i * 256 * 256;
    const short* outT_i  = outT + (long)i * 256 * 256;
    const short* f1T_i   = ffn1T + (long)i * 512 * 256;
    const short* f2T_i   = ffn2T + (long)i * 256 * 512;

    // off+aw scores -> comb bf16 [nq][256]
    gemm2_kernel<16, 4, 0><<<dim3(1, kNQ / 16), 256, 0, stream>>>(
        qp_bf, 0, kE, combT_i, 256, 256, 1, comb_b + i * 256,
        nullptr, comb_bf, 256, 0, nullptr, nullptr, nullptr, nullptr,
        nullptr, nullptr);
    // val = f @ val_w[i] (M = L*nq) -> bf16 (LDS-staged, BM=64)
    gemm2_kernel<64, 2, 0><<<dim3(1, kL * kNQ / 64), 256, 0, stream>>>(
        f_bf, 0, kC, valT_i, 256, 256, 1, val_b + (long)i * kE,
        nullptr, val_bf, kE, 0, nullptr, nullptr, nullptr, nullptr,
        nullptr, nullptr);
    // fused softmax + sampling
    sample_kernel<<<kNQ / 8, 256, 0, stream>>>((const unsigned short*)comb_bf,
                                               val_bf, accb);
    // out proj + residual + LN1 -> q fp32, qbf bf16
    gemm2_kernel<16, 4, 1><<<dim3(1, kNQ / 16), 256, 0, stream>>>(
        accb, 0, kE, outT_i, 256, 256, 1, out_b + (long)i * kE,
        q, qbf, 256, 0, q, ln1_g + (long)i * kE, ln1_b + (long)i * kE,
        nullptr, nullptr, nullptr);
    // FFN1 (N=512, relu) -> hid_bf (LDS-staged, BM=32)
    gemm2_kernel<32, 2, 0><<<dim3(2, kNQ / 32), 256, 0, stream>>>(
        qbf, 0, kE, f1T_i, 256, 256, 1, ffn_b1 + (long)i * kFF,
        nullptr, hid_bf, kFF, 1, nullptr, nullptr, nullptr, nullptr,
        nullptr, nullptr);
    // FFN2 (K=512) + residual + LN2 -> q fp32 (+ qp_bf for next layer)
    gemm2_kernel<16, 4, 1><<<dim3(1, kNQ / 16), 256, 0, stream>>>(
        hid_bf, 0, kFF, f2T_i, 512, 512, 1, ffn_b2 + (long)i * kE,
        q, nullptr, 256, 0, q, ln2_g + (long)i * kE, ln2_b + (long)i * kE,
        (i + 1 < kNL) ? qp_bf : nullptr, pos_row, pos_col);
  }

  transpose_kernel<<<dim3(kE / 32, kNQ / 32), 256, 0, stream>>>(q,
                                                                (float*)d_out);
}

// Round 11
// 1052.654 us; speedup vs baseline: 1.3377x; 1.0351x over previous
//
#include <hip/hip_runtime.h>
#include <hip/hip_bf16.h>
#include <stdint.h>

static constexpr int kL  = 5;
static constexpr int kNH = 4;
static constexpr int kP  = 4;
static constexpr int kE  = 256;
static constexpr int kC  = 256;
static constexpr int kH  = 128;
static constexpr int kW  = 128;
static constexpr int kNQ = kH * kW;          // 16384
static constexpr int kNL = 6;
static constexpr int kFF = 2 * kE;           // 512
static constexpr int kCOMB = 240;            // 160 off + 80 aw (stored ld 256)

typedef short bf16x8 __attribute__((ext_vector_type(8)));
typedef float f32x4 __attribute__((ext_vector_type(4)));

__device__ __forceinline__ short f2bf(float x) {
  union { float f; uint32_t u; } v; v.f = x;
  uint32_t r = v.u + 0x7fffu + ((v.u >> 16) & 1u);
  return (short)(r >> 16);
}
__device__ __forceinline__ uint32_t pack2(float a, float b) {
  return (uint32_t)(unsigned short)f2bf(a) | ((uint32_t)(unsigned short)f2bf(b) << 16);
}
__device__ __forceinline__ float bflo(uint32_t u) { return __uint_as_float(u << 16); }
__device__ __forceinline__ float bfhi(uint32_t u) { return __uint_as_float(u & 0xffff0000u); }
__device__ __forceinline__ float bf2f(unsigned short u) {
  return __uint_as_float((uint32_t)u << 16);
}

__device__ __forceinline__ void gl_lds16(const void* g, void* l) {
  __builtin_amdgcn_global_load_lds(
      (const __attribute__((address_space(1))) void*)g,
      (__attribute__((address_space(3))) void*)l, 16, 0, 0);
}

// ---------------------------------------------------------------------------
// LDS-staged bf16 MFMA GEMM, BN=256 per x-block. Waves WRxWC (WR=4/WC).
// Wave tile: (MT*16 rows) x (NT*16 cols). R7/R10-proven staging pattern
// (quad-per-row global reads; measured: bank aliasing here is the b128
// throughput floor, not a removable conflict — R7 == R10 A/B test).
// MODE 0: bias (+relu) -> Cf and/or Cb
// MODE 1: x=acc+bias+resid(RB: bf16|fp32); y=LN(x) -> Cf? Cb? qp?
// MODE 2: v=acc+bias -> Cf fp32, qp = bf16(v+pos)
// MODE 3 (BM=16,WC=4 only): MODE1 -> Cf fp32, then FUSED comb GEMM:
//         qpS(LDS) = bf16(y+pos); comb_out = qpS @ combT2^T + combB2
// ---------------------------------------------------------------------------
template <int BM, int WC, int MODE, int RB>
__global__ __launch_bounds__(256) void gemm2_kernel(
    const short* __restrict__ A, long sAb, int lda,
    const short* __restrict__ BT, int ldbt, int Kb, int nbatch,
    const float* __restrict__ bias,
    float* Cf, short* __restrict__ Cb, int ldc, int relu,
    const void* resid, const float* __restrict__ lng,
    const float* __restrict__ lnb, short* __restrict__ qp,
    const float* __restrict__ pos_row, const float* __restrict__ pos_col,
    const short* __restrict__ combT2, const float* __restrict__ combB2,
    short* __restrict__ comb_out) {
  static_assert(MODE != 3 || (BM == 16 && WC == 4), "MODE3 needs 16x256");
  constexpr int WR = 4 / WC;
  constexpr int MT = BM / (16 * WR);
  constexpr int NT = 16 / WC;
  constexpr int CW = 256 / WC;         // cols per wave
  constexpr int AI = BM / 16;          // A staging insts
  __shared__ short As[BM * 32];
  __shared__ short Bs[256 * 32];
  __shared__ float2 lnpart[(MODE == 1 || MODE == 3) ? BM : 1][WC];
  __shared__ short qpS[(MODE == 3) ? 16 * 272 : 1];
  const int tid = threadIdx.x;
  const int wave = tid >> 6, lane = tid & 63;
  const int wy = wave / WC, wx = wave % WC;
  const long row0 = (long)blockIdx.y * BM;
  const int col0 = blockIdx.x * 256;
  const int srow = lane >> 2;                        // quad-per-row staging
  const int skof = ((lane & 3) ^ (srow & 3)) * 8;
  const int fr = lane & 15, fq = lane >> 4;
  const int ua = (fr * 4 + (fq ^ (fr & 3))) * 8;     // fragment read offset
  f32x4 acc[MT][NT] = {};
  for (int bb = 0; bb < nbatch; ++bb) {
    const short* Ab = A + (long)bb * sAb + row0 * lda;
    const short* Bb = BT + (long)col0 * ldbt + (long)bb * Kb;
    for (int k0 = 0; k0 < Kb; k0 += 32) {
      __syncthreads();
      for (int t = wave; t < AI + 16; t += 4) {
        if (t < AI)
          gl_lds16(Ab + (long)(t * 16 + srow) * lda + k0 + skof, &As[t * 512]);
        else {
          int u = t - AI;
          gl_lds16(Bb + (long)(u * 16 + srow) * ldbt + k0 + skof, &Bs[u * 512]);
        }
      }
      __syncthreads();
      bf16x8 af[MT], bfv[NT];
#pragma unroll
      for (int t = 0; t < MT; ++t)
        af[t] = *(const bf16x8*)&As[(wy * MT + t) * 512 + ua];
#pragma unroll
      for (int t = 0; t < NT; ++t)
        bfv[t] = *(const bf16x8*)&Bs[(wx * (CW / 16) + t) * 512 + ua];
#pragma unroll
      for (int mt = 0; mt < MT; ++mt)
#pragma unroll
        for (int nt = 0; nt < NT; ++nt)
          acc[mt][nt] = __builtin_amdgcn_mfma_f32_16x16x32_bf16(
              af[mt], bfv[nt], acc[mt][nt], 0, 0, 0);
    }
  }
  const int colb = col0 + wx * CW + fr;            // + nt*16
  const long rowb = row0 + wy * MT * 16 + fq * 4;  // + mt*16 + rr

  if (MODE == 0) {
#pragma unroll
    for (int mt = 0; mt < MT; ++mt)
#pragma unroll
      for (int rr = 0; rr < 4; ++rr) {
        long row = rowb + mt * 16 + rr;
#pragma unroll
        for (int nt = 0; nt < NT; ++nt) {
          int col = colb + nt * 16;
          float v = acc[mt][nt][rr] + bias[col];
          if (relu) v = fmaxf(v, 0.f);
          if (Cf) Cf[row * ldc + col] = v;
          if (Cb) Cb[row * ldc + col] = f2bf(v);
        }
      }
  } else if (MODE == 2) {
#pragma unroll
    for (int mt = 0; mt < MT; ++mt)
#pragma unroll
      for (int rr = 0; rr < 4; ++rr) {
        long row = rowb + mt * 16 + rr;
        int wpos = (int)row & (kW - 1), hpos = (int)row >> 7;
#pragma unroll
        for (int nt = 0; nt < NT; ++nt) {
          int col = colb + nt * 16;
          float v = acc[mt][nt][rr] + bias[col];
          Cf[row * 256 + col] = v;
          float pv = (col < 128) ? pos_col[wpos * 128 + col]
                                 : pos_row[hpos * 128 + (col - 128)];
          qp[row * 256 + col] = f2bf(v + pv);
        }
      }
  } else {
    const float* residf = (const float*)resid;
    const unsigned short* residb = (const unsigned short*)resid;
#pragma unroll
    for (int mt = 0; mt < MT; ++mt)
#pragma unroll
      for (int rr = 0; rr < 4; ++rr) {
        long row = rowb + mt * 16 + rr;
        float s = 0.f, s2 = 0.f;
#pragma unroll
        for (int nt = 0; nt < NT; ++nt) {
          int col = colb + nt * 16;
          float rv = RB ? bf2f(residb[row * 256 + col])
                        : residf[row * 256 + col];
          float v = acc[mt][nt][rr] + bias[col] + rv;
          acc[mt][nt][rr] = v;
          s += v; s2 += v * v;
        }
#pragma unroll
        for (int o = 8; o > 0; o >>= 1) {
          s += __shfl_xor(s, o);
          s2 += __shfl_xor(s2, o);
        }
        if (fr == 0) {
          int rl = wy * MT * 16 + mt * 16 + fq * 4 + rr;
          lnpart[rl][wx] = make_float2(s, s2);
        }
      }
    __syncthreads();
#pragma unroll
    for (int mt = 0; mt < MT; ++mt)
#pragma unroll
      for (int rr = 0; rr < 4; ++rr) {
        int rl = wy * MT * 16 + mt * 16 + fq * 4 + rr;
        long row = rowb + mt * 16 + rr;
        float s = 0.f, s2 = 0.f;
#pragma unroll
        for (int c = 0; c < WC; ++c) {
          s += lnpart[rl][c].x; s2 += lnpart[rl][c].y;
        }
        float m = s * (1.f / 256);
        float var = s2 * (1.f / 256) - m * m;
        float rs = rsqrtf(var + 1e-5f);
        int wpos = (int)row & (kW - 1), hpos = (int)row >> 7;
#pragma unroll
        for (int nt = 0; nt < NT; ++nt) {
          int col = colb + nt * 16;
          float y = (acc[mt][nt][rr] - m) * rs * lng[col] + lnb[col];
          if (Cf) Cf[row * 256 + col] = y;
          if (MODE == 1 && Cb) Cb[row * 256 + col] = f2bf(y);
          if (MODE == 1 && qp) {
            float pv = (col < 128) ? pos_col[wpos * 128 + col]
                                   : pos_row[hpos * 128 + (col - 128)];
            qp[row * 256 + col] = f2bf(y + pv);
          }
          if (MODE == 3) {
            float pv = (col < 128) ? pos_col[wpos * 128 + col]
                                   : pos_row[hpos * 128 + (col - 128)];
            qpS[rl * 272 + col] = f2bf(y + pv);
          }
        }
      }
    if (MODE == 3) {
      __syncthreads();                 // qpS visible to all waves
      f32x4 acc2[NT] = {};
      for (int k0 = 0; k0 < 256; k0 += 32) {
        __syncthreads();
        for (int u = wave; u < 16; u += 4)
          gl_lds16(combT2 + (long)(u * 16 + srow) * 256 + k0 + skof,
                   &Bs[u * 512]);
        __syncthreads();
        bf16x8 av = *(const bf16x8*)&qpS[fr * 272 + k0 + fq * 8];
        bf16x8 bv[NT];
#pragma unroll
        for (int t = 0; t < NT; ++t)
          bv[t] = *(const bf16x8*)&Bs[(wx * (CW / 16) + t) * 512 + ua];
#pragma unroll
        for (int t = 0; t < NT; ++t)
          acc2[t] = __builtin_amdgcn_mfma_f32_16x16x32_bf16(av, bv[t],
                                                            acc2[t], 0, 0, 0);
      }
#pragma unroll
      for (int rr = 0; rr < 4; ++rr) {
        long row = row0 + fq * 4 + rr;
#pragma unroll
        for (int nt = 0; nt < NT; ++nt) {
          int col = colb + nt * 16;
          comb_out[row * 256 + col] = f2bf(acc2[nt][rr] + combB2[col]);
        }
      }
    }
  }
}

// ---------------------------------------------------------------------------
// weight convert+transpose: in fp32 [Z,K,N] -> out bf16 [Z,N,K]
__global__ __launch_bounds__(256) void wt_convert_kernel(
    const float* __restrict__ in, short* __restrict__ out, int K, int N) {
  long idx = (long)blockIdx.x * 256 + threadIdx.x;
  int z = blockIdx.y;
  int n = (int)(idx / K);
  int k = (int)(idx - (long)n * K);
  out[(long)z * N * K + idx] = f2bf(in[(long)z * K * N + (long)k * N + n]);
}

// off_w + aw_w -> combT bf16 [Z, 256 rows(n), 256(k)] + comb bias
__global__ __launch_bounds__(256) void comb_convert_kernel(
    const float* __restrict__ off_w, const float* __restrict__ aw_w,
    const float* __restrict__ off_b, const float* __restrict__ aw_b,
    short* __restrict__ combT, float* __restrict__ comb_bias) {
  int idx = blockIdx.x * 256 + threadIdx.x;
  int z = blockIdx.y;
  int n = idx >> 8, k = idx & 255;
  float v = 0.f;
  if (n < 160) v = off_w[((long)z * 256 + k) * 160 + n];
  else if (n < kCOMB) v = aw_w[((long)z * 256 + k) * 80 + (n - 160)];
  combT[(long)z * 65536 + idx] = f2bf(v);
  if (k == 0)
    comb_bias[z * 256 + n] =
        (n < 160) ? off_b[z * 160 + n]
                  : (n < kCOMB ? aw_b[z * 80 + (n - 160)] : 0.f);
}

// ---------------------------------------------------------------------------
// LN over channels of feat [L, C, nq]: stats
__global__ __launch_bounds__(256) void ln_stats_kernel(
    const float* __restrict__ feat, float* __restrict__ mean_out,
    float* __restrict__ rstd_out) {
  int i = blockIdx.x * 256 + threadIdx.x;
  int l = i >> 14;
  int n = i & (kNQ - 1);
  const float* base = feat + (long)l * kC * kNQ + n;
  float s = 0.f, s2 = 0.f;
  for (int c = 0; c < kC; ++c) {
    float v = base[(long)c * kNQ];
    s += v; s2 += v * v;
  }
  float m = s * (1.f / kC);
  float var = s2 * (1.f / kC) - m * m;
  mean_out[i] = m;
  rstd_out[i] = rsqrtf(var + 1e-5f);
}

// LN apply + transpose -> f bf16 [L, nq, C]
__global__ __launch_bounds__(256) void ln_apply_kernel(
    const float* __restrict__ feat, const float* __restrict__ mean_in,
    const float* __restrict__ rstd_in, const float* __restrict__ g,
    const float* __restrict__ b, short* __restrict__ f) {
  __shared__ float tile[32][33];
  int l  = blockIdx.z;
  int cb = blockIdx.x * 32, nb = blockIdx.y * 32;
  int tx = threadIdx.x & 31;
  int ty = threadIdx.x >> 5;
#pragma unroll
  for (int j = 0; j < 4; ++j) {
    int c = ty + j * 8;
    tile[c][tx] = feat[((long)(l * kC + cb + c)) * kNQ + nb + tx];
  }
  __syncthreads();
#pragma unroll
  for (int j = 0; j < 4; ++j) {
    int nl = ty + j * 8;
    int n  = nb + nl;
    float m  = mean_in[l * kNQ + n];
    float rs = rstd_in[l * kNQ + n];
    int c = cb + tx;
    float v = (tile[tx][nl] - m) * rs * g[l * kC + c] + b[l * kC + c];
    f[((long)l * kNQ + n) * kC + c] = f2bf(v);
  }
}

// ---------------------------------------------------------------------------
// Deformable sampling: wave handles 2 queries (32 lanes each), all 4 heads.
// comb is bf16 [nq][256]: offsets at h*40+lp*2, scores at 160+h*20+lp.
__global__ __launch_bounds__(256) void sample_kernel(
    const unsigned short* __restrict__ comb, const short* __restrict__ val,
    short* __restrict__ accb) {
  __shared__ float2 ic[4][2][4][85];
  int wv = threadIdx.x >> 6;
  int lane = threadIdx.x & 63;
  int half = lane >> 5;
  int hl = lane & 31;
  int n = blockIdx.x * 8 + wv * 2 + half;
  int wq = n & (kW - 1);
  int hq = n >> 7;
  const unsigned short* cb = comb + (long)n * 256;
#pragma unroll
  for (int h = 0; h < 4; ++h) {
    float raw = (hl < 20) ? bf2f(cb[160 + h * 20 + hl]) : -1e30f;
    float mx = raw;
#pragma unroll
    for (int o = 16; o > 0; o >>= 1) mx = fmaxf(mx, __shfl_xor(mx, o));
    float ev = (hl < 20) ? __expf(raw - mx) : 0.f;
    float se = ev;
#pragma unroll
    for (int o = 16; o > 0; o >>= 1) se += __shfl_xor(se, o);
    if (hl < 20) {
      float awv = ev / se;
      int l = hl >> 2;
      float ox = bf2f(cb[h * 40 + hl * 2 + 0]);
      float oy = bf2f(cb[h * 40 + hl * 2 + 1]);
      float x = (float)wq + ox;
      float y = (float)hq + oy;
      float x0f = floorf(x), y0f = floorf(y);
      float fx = x - x0f, fy = y - y0f;
      int x0 = (int)x0f, y0 = (int)y0f;
#pragma unroll
      for (int c = 0; c < 4; ++c) {
        int dx = c & 1, dy = c >> 1;
        int ix = x0 + dx, iy = y0 + dy;
        float wgt = (dx ? fx : 1.f - fx) * (dy ? fy : 1.f - fy);
        bool valid = (ix >= 0 && ix < kW && iy >= 0 && iy < kH);
        int cix = min(max(ix, 0), kW - 1);
        int ciy = min(max(iy, 0), kH - 1);
        int sidx = ciy * kW + cix;
        int byteoff = (l * kNQ + sidx) * (kE * 2);
        float coef = valid ? awv * wgt : 0.f;
        ic[wv][half][h][hl * 4 + c] = make_float2(__int_as_float(byteoff), coef);
      }
    }
  }
  __syncthreads();
  int h2 = (lane >> 3) & 3;
  int ch8 = (lane & 7) * 8;
  const char* vb = (const char*)val + (h2 * 64 + ch8) * 2;
  const float2* icp = &ic[wv][half][h2][0];
  float a0 = 0.f, a1 = 0.f, a2 = 0.f, a3 = 0.f;
  float a4 = 0.f, a5 = 0.f, a6 = 0.f, a7 = 0.f;
#pragma unroll 4
  for (int j = 0; j < 80; ++j) {
    float2 oc = icp[j];
    int off = __float_as_int(oc.x);
    uint4 u = *(const uint4*)(vb + off);
    float cf = oc.y;
    a0 += cf * bflo(u.x); a1 += cf * bfhi(u.x);
    a2 += cf * bflo(u.y); a3 += cf * bfhi(u.y);
    a4 += cf * bflo(u.z); a5 += cf * bfhi(u.z);
    a6 += cf * bflo(u.w); a7 += cf * bfhi(u.w);
  }
  uint4 o;
  o.x = pack2(a0, a1); o.y = pack2(a2, a3);
  o.z = pack2(a4, a5); o.w = pack2(a6, a7);
  *(uint4*)(accb + (long)n * kE + h2 * 64 + ch8) = o;
}

// final transpose: out[e, n] = q[n, e]
__global__ __launch_bounds__(256) void transpose_kernel(
    const float* __restrict__ q, float* __restrict__ out) {
  __shared__ float t[32][33];
  int eb = blockIdx.x * 32, nb = blockIdx.y * 32;
  int tx = threadIdx.x & 31, ty = threadIdx.x >> 5;
#pragma unroll
  for (int j = 0; j < 4; ++j)
    t[ty + j * 8][tx] = q[(long)(nb + ty + j * 8) * kE + eb + tx];
  __syncthreads();
#pragma unroll
  for (int j = 0; j < 4; ++j)
    out[(long)(eb + ty + j * 8) * kNQ + nb + tx] = t[tx][ty + j * 8];
}

extern "C" void kernel_launch(void* const* d_in, const int* in_sizes, int n_in,
                              void* d_out, int out_size, void* d_ws,
                              size_t ws_size, hipStream_t stream) {
  const float* feat    = (const float*)d_in[0];
  const float* norm0_g = (const float*)d_in[1];
  const float* norm0_b = (const float*)d_in[2];
  const float* in_w    = (const float*)d_in[3];
  const float* in_b    = (const float*)d_in[4];
  const float* pos_row = (const float*)d_in[5];
  const float* pos_col = (const float*)d_in[6];
  const float* off_w   = (const float*)d_in[7];
  const float* off_b   = (const float*)d_in[8];
  const float* aw_w    = (const float*)d_in[9];
  const float* aw_b    = (const float*)d_in[10];
  const float* val_w   = (const float*)d_in[11];
  const float* val_b   = (const float*)d_in[12];
  const float* out_w   = (const float*)d_in[13];
  const float* out_b   = (const float*)d_in[14];
  const float* ln1_g   = (const float*)d_in[15];
  const float* ln1_b   = (const float*)d_in[16];
  const float* ln2_g   = (const float*)d_in[17];
  const float* ln2_b   = (const float*)d_in[18];
  const float* ffn_w1  = (const float*)d_in[19];
  const float* ffn_b1  = (const float*)d_in[20];
  const float* ffn_w2  = (const float*)d_in[21];
  const float* ffn_b2  = (const float*)d_in[22];

  char* p = (char*)d_ws;
  auto alloc = [&](size_t bytes) -> char* {
    char* r = p;
    p += (bytes + 255) & ~(size_t)255;
    return r;
  };
  short* f_bf    = (short*)alloc((size_t)kL * kNQ * kC * 2);
  short* val_bf  = (short*)alloc((size_t)kL * kNQ * kE * 2);
  float* q       = (float*)alloc((size_t)kNQ * kE * 4);
  short* qbf     = (short*)alloc((size_t)kNQ * kE * 2);
  short* qp_bf   = (short*)alloc((size_t)kNQ * kE * 2);
  short* accb    = (short*)alloc((size_t)kNQ * kE * 2);
  short* hid_bf  = (short*)alloc((size_t)kNQ * kFF * 2);
  short* comb_bf = (short*)alloc((size_t)kNQ * 256 * 2);
  float* comb_b  = (float*)alloc((size_t)kNL * 256 * 4);
  float* meanb   = (float*)alloc((size_t)kL * kNQ * 4);
  float* rstdb   = (float*)alloc((size_t)kL * kNQ * 4);
  short* inT     = (short*)alloc((size_t)256 * 1280 * 2);
  short* valT    = (short*)alloc((size_t)kNL * 256 * 256 * 2);
  short* outT    = (short*)alloc((size_t)kNL * 256 * 256 * 2);
  short* ffn1T   = (short*)alloc((size_t)kNL * 512 * 256 * 2);
  short* ffn2T   = (short*)alloc((size_t)kNL * 256 * 512 * 2);
  short* combT   = (short*)alloc((size_t)kNL * 256 * 256 * 2);

  // weight conversions (bf16, transposed to [N,K])
  wt_convert_kernel<<<dim3(1280, 1), 256, 0, stream>>>(in_w, inT, 1280, 256);
  wt_convert_kernel<<<dim3(256, kNL), 256, 0, stream>>>(val_w, valT, 256, 256);
  wt_convert_kernel<<<dim3(256, kNL), 256, 0, stream>>>(out_w, outT, 256, 256);
  wt_convert_kernel<<<dim3(512, kNL), 256, 0, stream>>>(ffn_w1, ffn1T, 256, 512);
  wt_convert_kernel<<<dim3(512, kNL), 256, 0, stream>>>(ffn_w2, ffn2T, 512, 256);
  comb_convert_kernel<<<dim3(256, kNL), 256, 0, stream>>>(off_w, aw_w, off_b,
                                                          aw_b, combT, comb_b);

  // feature LN -> f bf16
  ln_stats_kernel<<<kL * kNQ / 256, 256, 0, stream>>>(feat, meanb, rstdb);
  ln_apply_kernel<<<dim3(kC / 32, kNQ / 32, kL), 256, 0, stream>>>(
      feat, meanb, rstdb, norm0_g, norm0_b, f_bf);

  // input proj + pos-add epilogue: q fp32, qp_bf bf16
  gemm2_kernel<16, 4, 2, 0><<<dim3(1, kNQ / 16), 256, 0, stream>>>(
      f_bf, (long)kNQ * kC, kC, inT, 1280, 256, kL, in_b,
      q, nullptr, 256, 0, nullptr, nullptr, nullptr, qp_bf, pos_row, pos_col,
      nullptr, nullptr, nullptr);
  // layer-0 off+aw scores (standalone; later layers come fused from MODE3)
  gemm2_kernel<16, 4, 0, 0><<<dim3(1, kNQ / 16), 256, 0, stream>>>(
      qp_bf, 0, kE, combT, 256, 256, 1, comb_b,
      nullptr, comb_bf, 256, 0, nullptr, nullptr, nullptr, nullptr,
      nullptr, nullptr, nullptr, nullptr, nullptr);

  for (int i = 0; i < kNL; ++i) {
    const short* valT_i  = valT + (long)i * 256 * 256;
    const short* outT_i  = outT + (long)i * 256 * 256;
    const short* f1T_i   = ffn1T + (long)i * 512 * 256;
    const short* f2T_i   = ffn2T + (long)i * 256 * 512;

    // val = f @ val_w[i] (M = L*nq) -> bf16 (LDS-staged, BM=64)
    gemm2_kernel<64, 2, 0, 0><<<dim3(1, kL * kNQ / 64), 256, 0, stream>>>(
        f_bf, 0, kC, valT_i, 256, 256, 1, val_b + (long)i * kE,
        nullptr, val_bf, kE, 0, nullptr, nullptr, nullptr, nullptr,
        nullptr, nullptr, nullptr, nullptr, nullptr);
    // fused softmax + sampling
    sample_kernel<<<kNQ / 8, 256, 0, stream>>>((const unsigned short*)comb_bf,
                                               val_bf, accb);
    // out proj + residual(q fp32) + LN1 -> qbf (bf16 only)
    gemm2_kernel<16, 4, 1, 0><<<dim3(1, kNQ / 16), 256, 0, stream>>>(
        accb, 0, kE, outT_i, 256, 256, 1, out_b + (long)i * kE,
        nullptr, qbf, 256, 0, q, ln1_g + (long)i * kE, ln1_b + (long)i * kE,
        nullptr, nullptr, nullptr, nullptr, nullptr, nullptr);
    // FFN1 (N=512, relu) -> hid_bf (LDS-staged, BM=32)
    gemm2_kernel<32, 2, 0, 0><<<dim3(2, kNQ / 32), 256, 0, stream>>>(
        qbf, 0, kE, f1T_i, 256, 256, 1, ffn_b1 + (long)i * kFF,
        nullptr, hid_bf, kFF, 1, nullptr, nullptr, nullptr, nullptr,
        nullptr, nullptr, nullptr, nullptr, nullptr);
    // FFN2 (K=512) + residual(qbf bf16) + LN2 -> q fp32
    if (i + 1 < kNL) {
      // + fused comb GEMM for layer i+1
      gemm2_kernel<16, 4, 3, 1><<<dim3(1, kNQ / 16), 256, 0, stream>>>(
          hid_bf, 0, kFF, f2T_i, 512, 512, 1, ffn_b2 + (long)i * kE,
          q, nullptr, 256, 0, qbf, ln2_g + (long)i * kE,
          ln2_b + (long)i * kE, nullptr, pos_row, pos_col,
          combT + (long)(i + 1) * 256 * 256, comb_b + (i + 1) * 256, comb_bf);
    } else {
      gemm2_kernel<16, 4, 1, 1><<<dim3(1, kNQ / 16), 256, 0, stream>>>(
          hid_bf, 0, kFF, f2T_i, 512, 512, 1, ffn_b2 + (long)i * kE,
          q, nullptr, 256, 0, qbf, ln2_g + (long)i * kE,
          ln2_b + (long)i * kE, nullptr, nullptr, nullptr,
          nullptr, nullptr, nullptr);
    }
  }

  transpose_kernel<<<dim3(kE / 32, kNQ / 32), 256, 0, stream>>>(q,
                                                                (float*)d_out);
}

// Round 12
// 1050.041 us; speedup vs baseline: 1.3411x; 1.0025x over previous
//
#include <hip/hip_runtime.h>
#include <hip/hip_bf16.h>
#include <stdint.h>

static constexpr int kL  = 5;
static constexpr int kNH = 4;
static constexpr int kP  = 4;
static constexpr int kE  = 256;
static constexpr int kC  = 256;
static constexpr int kH  = 128;
static constexpr int kW  = 128;
static constexpr int kNQ = kH * kW;          // 16384
static constexpr int kNL = 6;
static constexpr int kFF = 2 * kE;           // 512
static constexpr int kCOMB = 240;            // 160 off + 80 aw (stored ld 256)

typedef short bf16x8 __attribute__((ext_vector_type(8)));
typedef float f32x4 __attribute__((ext_vector_type(4)));

__device__ __forceinline__ short f2bf(float x) {
  union { float f; uint32_t u; } v; v.f = x;
  uint32_t r = v.u + 0x7fffu + ((v.u >> 16) & 1u);
  return (short)(r >> 16);
}
__device__ __forceinline__ uint32_t pack2(float a, float b) {
  return (uint32_t)(unsigned short)f2bf(a) | ((uint32_t)(unsigned short)f2bf(b) << 16);
}
__device__ __forceinline__ float bflo(uint32_t u) { return __uint_as_float(u << 16); }
__device__ __forceinline__ float bfhi(uint32_t u) { return __uint_as_float(u & 0xffff0000u); }
__device__ __forceinline__ float bf2f(unsigned short u) {
  return __uint_as_float((uint32_t)u << 16);
}

__device__ __forceinline__ void gl_lds16(const void* g, void* l) {
  __builtin_amdgcn_global_load_lds(
      (const __attribute__((address_space(1))) void*)g,
      (__attribute__((address_space(3))) void*)l, 16, 0, 0);
}

// ---------------------------------------------------------------------------
// LDS-staged bf16 MFMA GEMM, BN=256 per x-block. Waves WRxWC (WR=4/WC).
// Wave tile: (MT*16 rows) x (NT*16 cols). R7/R10-proven staging pattern.
// MODE 0: bias (+relu) -> Cf and/or Cb
// MODE 1: x=acc+bias+resid(RB: bf16|fp32); y=LN(x) -> Cf? Cb? qp?
// MODE 2: v=acc+bias -> Cf fp32, qp = bf16(v+pos)
// MODE 3 (16x256): MODE1 -> Cf, then fused GEMM2:
//         qpS = bf16(y+pos); out2 = qpS @ w2^T + b2          (comb, N=256)
// MODE 4 (16x256): MODE1 -> Cb(qbf), then fused GEMM2:
//         qpS = bf16(y);     out2 = relu(qpS @ w2^T + b2)    (ffn1, N=512,
//         two 256-col halves reusing Bs)
// ---------------------------------------------------------------------------
template <int BM, int WC, int MODE, int RB>
__global__ __launch_bounds__(256) void gemm2_kernel(
    const short* __restrict__ A, long sAb, int lda,
    const short* __restrict__ BT, int ldbt, int Kb, int nbatch,
    const float* __restrict__ bias,
    float* Cf, short* __restrict__ Cb, int ldc, int relu,
    const void* resid, const float* __restrict__ lng,
    const float* __restrict__ lnb, short* __restrict__ qp,
    const float* __restrict__ pos_row, const float* __restrict__ pos_col,
    const short* __restrict__ w2BT, const float* __restrict__ w2B,
    short* __restrict__ out2) {
  static_assert((MODE != 3 && MODE != 4) || (BM == 16 && WC == 4),
                "fused modes need 16x256");
  constexpr int WR = 4 / WC;
  constexpr int MT = BM / (16 * WR);
  constexpr int NT = 16 / WC;
  constexpr int CW = 256 / WC;         // cols per wave
  constexpr int AI = BM / 16;          // A staging insts
  __shared__ short As[BM * 32];
  __shared__ short Bs[256 * 32];
  __shared__ float2 lnpart[(MODE >= 1 && MODE != 2) ? BM : 1][WC];
  __shared__ short qpS[(MODE == 3 || MODE == 4) ? 16 * 280 : 1];
  const int tid = threadIdx.x;
  const int wave = tid >> 6, lane = tid & 63;
  const int wy = wave / WC, wx = wave % WC;
  const long row0 = (long)blockIdx.y * BM;
  const int col0 = blockIdx.x * 256;
  const int srow = lane >> 2;                        // quad-per-row staging
  const int skof = ((lane & 3) ^ (srow & 3)) * 8;
  const int fr = lane & 15, fq = lane >> 4;
  const int ua = (fr * 4 + (fq ^ (fr & 3))) * 8;     // fragment read offset
  f32x4 acc[MT][NT] = {};
  for (int bb = 0; bb < nbatch; ++bb) {
    const short* Ab = A + (long)bb * sAb + row0 * lda;
    const short* Bb = BT + (long)col0 * ldbt + (long)bb * Kb;
    for (int k0 = 0; k0 < Kb; k0 += 32) {
      __syncthreads();
      for (int t = wave; t < AI + 16; t += 4) {
        if (t < AI)
          gl_lds16(Ab + (long)(t * 16 + srow) * lda + k0 + skof, &As[t * 512]);
        else {
          int u = t - AI;
          gl_lds16(Bb + (long)(u * 16 + srow) * ldbt + k0 + skof, &Bs[u * 512]);
        }
      }
      __syncthreads();
      bf16x8 af[MT], bfv[NT];
#pragma unroll
      for (int t = 0; t < MT; ++t)
        af[t] = *(const bf16x8*)&As[(wy * MT + t) * 512 + ua];
#pragma unroll
      for (int t = 0; t < NT; ++t)
        bfv[t] = *(const bf16x8*)&Bs[(wx * (CW / 16) + t) * 512 + ua];
#pragma unroll
      for (int mt = 0; mt < MT; ++mt)
#pragma unroll
        for (int nt = 0; nt < NT; ++nt)
          acc[mt][nt] = __builtin_amdgcn_mfma_f32_16x16x32_bf16(
              af[mt], bfv[nt], acc[mt][nt], 0, 0, 0);
    }
  }
  const int colb = col0 + wx * CW + fr;            // + nt*16
  const long rowb = row0 + wy * MT * 16 + fq * 4;  // + mt*16 + rr

  if (MODE == 0) {
#pragma unroll
    for (int mt = 0; mt < MT; ++mt)
#pragma unroll
      for (int rr = 0; rr < 4; ++rr) {
        long row = rowb + mt * 16 + rr;
#pragma unroll
        for (int nt = 0; nt < NT; ++nt) {
          int col = colb + nt * 16;
          float v = acc[mt][nt][rr] + bias[col];
          if (relu) v = fmaxf(v, 0.f);
          if (Cf) Cf[row * ldc + col] = v;
          if (Cb) Cb[row * ldc + col] = f2bf(v);
        }
      }
  } else if (MODE == 2) {
#pragma unroll
    for (int mt = 0; mt < MT; ++mt)
#pragma unroll
      for (int rr = 0; rr < 4; ++rr) {
        long row = rowb + mt * 16 + rr;
        int wpos = (int)row & (kW - 1), hpos = (int)row >> 7;
#pragma unroll
        for (int nt = 0; nt < NT; ++nt) {
          int col = colb + nt * 16;
          float v = acc[mt][nt][rr] + bias[col];
          Cf[row * 256 + col] = v;
          float pv = (col < 128) ? pos_col[wpos * 128 + col]
                                 : pos_row[hpos * 128 + (col - 128)];
          qp[row * 256 + col] = f2bf(v + pv);
        }
      }
  } else {
    const float* residf = (const float*)resid;
    const unsigned short* residb = (const unsigned short*)resid;
#pragma unroll
    for (int mt = 0; mt < MT; ++mt)
#pragma unroll
      for (int rr = 0; rr < 4; ++rr) {
        long row = rowb + mt * 16 + rr;
        float s = 0.f, s2 = 0.f;
#pragma unroll
        for (int nt = 0; nt < NT; ++nt) {
          int col = colb + nt * 16;
          float rv = RB ? bf2f(residb[row * 256 + col])
                        : residf[row * 256 + col];
          float v = acc[mt][nt][rr] + bias[col] + rv;
          acc[mt][nt][rr] = v;
          s += v; s2 += v * v;
        }
#pragma unroll
        for (int o = 8; o > 0; o >>= 1) {
          s += __shfl_xor(s, o);
          s2 += __shfl_xor(s2, o);
        }
        if (fr == 0) {
          int rl = wy * MT * 16 + mt * 16 + fq * 4 + rr;
          lnpart[rl][wx] = make_float2(s, s2);
        }
      }
    __syncthreads();
#pragma unroll
    for (int mt = 0; mt < MT; ++mt)
#pragma unroll
      for (int rr = 0; rr < 4; ++rr) {
        int rl = wy * MT * 16 + mt * 16 + fq * 4 + rr;
        long row = rowb + mt * 16 + rr;
        float s = 0.f, s2 = 0.f;
#pragma unroll
        for (int c = 0; c < WC; ++c) {
          s += lnpart[rl][c].x; s2 += lnpart[rl][c].y;
        }
        float m = s * (1.f / 256);
        float var = s2 * (1.f / 256) - m * m;
        float rs = rsqrtf(var + 1e-5f);
        int wpos = (int)row & (kW - 1), hpos = (int)row >> 7;
#pragma unroll
        for (int nt = 0; nt < NT; ++nt) {
          int col = colb + nt * 16;
          float y = (acc[mt][nt][rr] - m) * rs * lng[col] + lnb[col];
          if (Cf) Cf[row * 256 + col] = y;
          if (MODE != 3 && Cb) Cb[row * 256 + col] = f2bf(y);
          if (MODE == 1 && qp) {
            float pv = (col < 128) ? pos_col[wpos * 128 + col]
                                   : pos_row[hpos * 128 + (col - 128)];
            qp[row * 256 + col] = f2bf(y + pv);
          }
          if (MODE == 3) {
            float pv = (col < 128) ? pos_col[wpos * 128 + col]
                                   : pos_row[hpos * 128 + (col - 128)];
            qpS[rl * 280 + col] = f2bf(y + pv);
          }
          if (MODE == 4) qpS[rl * 280 + col] = f2bf(y);
        }
      }
    if (MODE == 3 || MODE == 4) {
      __syncthreads();                 // qpS visible to all waves
      constexpr int NHALF = (MODE == 4) ? 2 : 1;
      constexpr int ld2 = (MODE == 4) ? 512 : 256;
#pragma unroll
      for (int hf = 0; hf < NHALF; ++hf) {
        f32x4 acc2[NT] = {};
        for (int k0 = 0; k0 < 256; k0 += 32) {
          __syncthreads();
          for (int u = wave; u < 16; u += 4)
            gl_lds16(w2BT + (long)(hf * 256 + u * 16 + srow) * 256 + k0 + skof,
                     &Bs[u * 512]);
          __syncthreads();
          bf16x8 av = *(const bf16x8*)&qpS[fr * 280 + k0 + fq * 8];
          bf16x8 bv[NT];
#pragma unroll
          for (int t = 0; t < NT; ++t)
            bv[t] = *(const bf16x8*)&Bs[(wx * 4 + t) * 512 + ua];
#pragma unroll
          for (int t = 0; t < NT; ++t)
            acc2[t] = __builtin_amdgcn_mfma_f32_16x16x32_bf16(av, bv[t],
                                                              acc2[t], 0, 0, 0);
        }
#pragma unroll
        for (int rr = 0; rr < 4; ++rr) {
          long row = row0 + fq * 4 + rr;
#pragma unroll
          for (int nt = 0; nt < NT; ++nt) {
            int oc = hf * 256 + wx * 64 + nt * 16 + fr;
            float v = acc2[nt][rr] + w2B[oc];
            if (MODE == 4) v = fmaxf(v, 0.f);
            out2[row * ld2 + oc] = f2bf(v);
          }
        }
      }
    }
  }
}

// ---------------------------------------------------------------------------
// weight convert+transpose: in fp32 [Z,K,N] -> out bf16 [Z,N,K]
__global__ __launch_bounds__(256) void wt_convert_kernel(
    const float* __restrict__ in, short* __restrict__ out, int K, int N) {
  long idx = (long)blockIdx.x * 256 + threadIdx.x;
  int z = blockIdx.y;
  int n = (int)(idx / K);
  int k = (int)(idx - (long)n * K);
  out[(long)z * N * K + idx] = f2bf(in[(long)z * K * N + (long)k * N + n]);
}

// off_w + aw_w -> combT bf16 [Z, 256 rows(n), 256(k)] + comb bias
__global__ __launch_bounds__(256) void comb_convert_kernel(
    const float* __restrict__ off_w, const float* __restrict__ aw_w,
    const float* __restrict__ off_b, const float* __restrict__ aw_b,
    short* __restrict__ combT, float* __restrict__ comb_bias) {
  int idx = blockIdx.x * 256 + threadIdx.x;
  int z = blockIdx.y;
  int n = idx >> 8, k = idx & 255;
  float v = 0.f;
  if (n < 160) v = off_w[((long)z * 256 + k) * 160 + n];
  else if (n < kCOMB) v = aw_w[((long)z * 256 + k) * 80 + (n - 160)];
  combT[(long)z * 65536 + idx] = f2bf(v);
  if (k == 0)
    comb_bias[z * 256 + n] =
        (n < 160) ? off_b[z * 160 + n]
                  : (n < kCOMB ? aw_b[z * 80 + (n - 160)] : 0.f);
}

// ---------------------------------------------------------------------------
// LN over channels of feat [L, C, nq]: stats
__global__ __launch_bounds__(256) void ln_stats_kernel(
    const float* __restrict__ feat, float* __restrict__ mean_out,
    float* __restrict__ rstd_out) {
  int i = blockIdx.x * 256 + threadIdx.x;
  int l = i >> 14;
  int n = i & (kNQ - 1);
  const float* base = feat + (long)l * kC * kNQ + n;
  float s = 0.f, s2 = 0.f;
  for (int c = 0; c < kC; ++c) {
    float v = base[(long)c * kNQ];
    s += v; s2 += v * v;
  }
  float m = s * (1.f / kC);
  float var = s2 * (1.f / kC) - m * m;
  mean_out[i] = m;
  rstd_out[i] = rsqrtf(var + 1e-5f);
}

// LN apply + transpose -> f bf16 [L, nq, C]
__global__ __launch_bounds__(256) void ln_apply_kernel(
    const float* __restrict__ feat, const float* __restrict__ mean_in,
    const float* __restrict__ rstd_in, const float* __restrict__ g,
    const float* __restrict__ b, short* __restrict__ f) {
  __shared__ float tile[32][33];
  int l  = blockIdx.z;
  int cb = blockIdx.x * 32, nb = blockIdx.y * 32;
  int tx = threadIdx.x & 31;
  int ty = threadIdx.x >> 5;
#pragma unroll
  for (int j = 0; j < 4; ++j) {
    int c = ty + j * 8;
    tile[c][tx] = feat[((long)(l * kC + cb + c)) * kNQ + nb + tx];
  }
  __syncthreads();
#pragma unroll
  for (int j = 0; j < 4; ++j) {
    int nl = ty + j * 8;
    int n  = nb + nl;
    float m  = mean_in[l * kNQ + n];
    float rs = rstd_in[l * kNQ + n];
    int c = cb + tx;
    float v = (tile[tx][nl] - m) * rs * g[l * kC + c] + b[l * kC + c];
    f[((long)l * kNQ + n) * kC + c] = f2bf(v);
  }
}

// ---------------------------------------------------------------------------
// Deformable sampling: wave handles 2 queries (32 lanes each), all 4 heads.
// comb is bf16 [nq][256]: offsets at h*40+lp*2, scores at 160+h*20+lp.
__global__ __launch_bounds__(256) void sample_kernel(
    const unsigned short* __restrict__ comb, const short* __restrict__ val,
    short* __restrict__ accb) {
  __shared__ float2 ic[4][2][4][85];
  int wv = threadIdx.x >> 6;
  int lane = threadIdx.x & 63;
  int half = lane >> 5;
  int hl = lane & 31;
  int n = blockIdx.x * 8 + wv * 2 + half;
  int wq = n & (kW - 1);
  int hq = n >> 7;
  const unsigned short* cb = comb + (long)n * 256;
#pragma unroll
  for (int h = 0; h < 4; ++h) {
    float raw = (hl < 20) ? bf2f(cb[160 + h * 20 + hl]) : -1e30f;
    float mx = raw;
#pragma unroll
    for (int o = 16; o > 0; o >>= 1) mx = fmaxf(mx, __shfl_xor(mx, o));
    float ev = (hl < 20) ? __expf(raw - mx) : 0.f;
    float se = ev;
#pragma unroll
    for (int o = 16; o > 0; o >>= 1) se += __shfl_xor(se, o);
    if (hl < 20) {
      float awv = ev / se;
      int l = hl >> 2;
      float ox = bf2f(cb[h * 40 + hl * 2 + 0]);
      float oy = bf2f(cb[h * 40 + hl * 2 + 1]);
      float x = (float)wq + ox;
      float y = (float)hq + oy;
      float x0f = floorf(x), y0f = floorf(y);
      float fx = x - x0f, fy = y - y0f;
      int x0 = (int)x0f, y0 = (int)y0f;
#pragma unroll
      for (int c = 0; c < 4; ++c) {
        int dx = c & 1, dy = c >> 1;
        int ix = x0 + dx, iy = y0 + dy;
        float wgt = (dx ? fx : 1.f - fx) * (dy ? fy : 1.f - fy);
        bool valid = (ix >= 0 && ix < kW && iy >= 0 && iy < kH);
        int cix = min(max(ix, 0), kW - 1);
        int ciy = min(max(iy, 0), kH - 1);
        int sidx = ciy * kW + cix;
        int byteoff = (l * kNQ + sidx) * (kE * 2);
        float coef = valid ? awv * wgt : 0.f;
        ic[wv][half][h][hl * 4 + c] = make_float2(__int_as_float(byteoff), coef);
      }
    }
  }
  __syncthreads();
  int h2 = (lane >> 3) & 3;
  int ch8 = (lane & 7) * 8;
  const char* vb = (const char*)val + (h2 * 64 + ch8) * 2;
  const float2* icp = &ic[wv][half][h2][0];
  float a0 = 0.f, a1 = 0.f, a2 = 0.f, a3 = 0.f;
  float a4 = 0.f, a5 = 0.f, a6 = 0.f, a7 = 0.f;
#pragma unroll 4
  for (int j = 0; j < 80; ++j) {
    float2 oc = icp[j];
    int off = __float_as_int(oc.x);
    uint4 u = *(const uint4*)(vb + off);
    float cf = oc.y;
    a0 += cf * bflo(u.x); a1 += cf * bfhi(u.x);
    a2 += cf * bflo(u.y); a3 += cf * bfhi(u.y);
    a4 += cf * bflo(u.z); a5 += cf * bfhi(u.z);
    a6 += cf * bflo(u.w); a7 += cf * bfhi(u.w);
  }
  uint4 o;
  o.x = pack2(a0, a1); o.y = pack2(a2, a3);
  o.z = pack2(a4, a5); o.w = pack2(a6, a7);
  *(uint4*)(accb + (long)n * kE + h2 * 64 + ch8) = o;
}

// final transpose: out[e, n] = q[n, e]
__global__ __launch_bounds__(256) void transpose_kernel(
    const float* __restrict__ q, float* __restrict__ out) {
  __shared__ float t[32][33];
  int eb = blockIdx.x * 32, nb = blockIdx.y * 32;
  int tx = threadIdx.x & 31, ty = threadIdx.x >> 5;
#pragma unroll
  for (int j = 0; j < 4; ++j)
    t[ty + j * 8][tx] = q[(long)(nb + ty + j * 8) * kE + eb + tx];
  __syncthreads();
#pragma unroll
  for (int j = 0; j < 4; ++j)
    out[(long)(eb + ty + j * 8) * kNQ + nb + tx] = t[tx][ty + j * 8];
}

extern "C" void kernel_launch(void* const* d_in, const int* in_sizes, int n_in,
                              void* d_out, int out_size, void* d_ws,
                              size_t ws_size, hipStream_t stream) {
  const float* feat    = (const float*)d_in[0];
  const float* norm0_g = (const float*)d_in[1];
  const float* norm0_b = (const float*)d_in[2];
  const float* in_w    = (const float*)d_in[3];
  const float* in_b    = (const float*)d_in[4];
  const float* pos_row = (const float*)d_in[5];
  const float* pos_col = (const float*)d_in[6];
  const float* off_w   = (const float*)d_in[7];
  const float* off_b   = (const float*)d_in[8];
  const float* aw_w    = (const float*)d_in[9];
  const float* aw_b    = (const float*)d_in[10];
  const float* val_w   = (const float*)d_in[11];
  const float* val_b   = (const float*)d_in[12];
  const float* out_w   = (const float*)d_in[13];
  const float* out_b   = (const float*)d_in[14];
  const float* ln1_g   = (const float*)d_in[15];
  const float* ln1_b   = (const float*)d_in[16];
  const float* ln2_g   = (const float*)d_in[17];
  const float* ln2_b   = (const float*)d_in[18];
  const float* ffn_w1  = (const float*)d_in[19];
  const float* ffn_b1  = (const float*)d_in[20];
  const float* ffn_w2  = (const float*)d_in[21];
  const float* ffn_b2  = (const float*)d_in[22];

  char* p = (char*)d_ws;
  auto alloc = [&](size_t bytes) -> char* {
    char* r = p;
    p += (bytes + 255) & ~(size_t)255;
    return r;
  };
  short* f_bf    = (short*)alloc((size_t)kL * kNQ * kC * 2);
  short* val_bf  = (short*)alloc((size_t)kL * kNQ * kE * 2);
  float* q       = (float*)alloc((size_t)kNQ * kE * 4);
  short* qbf     = (short*)alloc((size_t)kNQ * kE * 2);
  short* qp_bf   = (short*)alloc((size_t)kNQ * kE * 2);
  short* accb    = (short*)alloc((size_t)kNQ * kE * 2);
  short* hid_bf  = (short*)alloc((size_t)kNQ * kFF * 2);
  short* comb_bf = (short*)alloc((size_t)kNQ * 256 * 2);
  float* comb_b  = (float*)alloc((size_t)kNL * 256 * 4);
  float* meanb   = (float*)alloc((size_t)kL * kNQ * 4);
  float* rstdb   = (float*)alloc((size_t)kL * kNQ * 4);
  short* inT     = (short*)alloc((size_t)256 * 1280 * 2);
  short* valT    = (short*)alloc((size_t)kNL * 256 * 256 * 2);
  short* outT    = (short*)alloc((size_t)kNL * 256 * 256 * 2);
  short* ffn1T   = (short*)alloc((size_t)kNL * 512 * 256 * 2);
  short* ffn2T   = (short*)alloc((size_t)kNL * 256 * 512 * 2);
  short* combT   = (short*)alloc((size_t)kNL * 256 * 256 * 2);

  // weight conversions (bf16, transposed to [N,K])
  wt_convert_kernel<<<dim3(1280, 1), 256, 0, stream>>>(in_w, inT, 1280, 256);
  wt_convert_kernel<<<dim3(256, kNL), 256, 0, stream>>>(val_w, valT, 256, 256);
  wt_convert_kernel<<<dim3(256, kNL), 256, 0, stream>>>(out_w, outT, 256, 256);
  wt_convert_kernel<<<dim3(512, kNL), 256, 0, stream>>>(ffn_w1, ffn1T, 256, 512);
  wt_convert_kernel<<<dim3(512, kNL), 256, 0, stream>>>(ffn_w2, ffn2T, 512, 256);
  comb_convert_kernel<<<dim3(256, kNL), 256, 0, stream>>>(off_w, aw_w, off_b,
                                                          aw_b, combT, comb_b);

  // feature LN -> f bf16
  ln_stats_kernel<<<kL * kNQ / 256, 256, 0, stream>>>(feat, meanb, rstdb);
  ln_apply_kernel<<<dim3(kC / 32, kNQ / 32, kL), 256, 0, stream>>>(
      feat, meanb, rstdb, norm0_g, norm0_b, f_bf);

  // input proj + pos-add epilogue: q fp32, qp_bf bf16
  gemm2_kernel<16, 4, 2, 0><<<dim3(1, kNQ / 16), 256, 0, stream>>>(
      f_bf, (long)kNQ * kC, kC, inT, 1280, 256, kL, in_b,
      q, nullptr, 256, 0, nullptr, nullptr, nullptr, qp_bf, pos_row, pos_col,
      nullptr, nullptr, nullptr);
  // layer-0 off+aw scores (standalone; later layers come fused from MODE3)
  gemm2_kernel<16, 4, 0, 0><<<dim3(1, kNQ / 16), 256, 0, stream>>>(
      qp_bf, 0, kE, combT, 256, 256, 1, comb_b,
      nullptr, comb_bf, 256, 0, nullptr, nullptr, nullptr, nullptr,
      nullptr, nullptr, nullptr, nullptr, nullptr);

  for (int i = 0; i < kNL; ++i) {
    const short* valT_i  = valT + (long)i * 256 * 256;
    const short* outT_i  = outT + (long)i * 256 * 256;
    const short* f1T_i   = ffn1T + (long)i * 512 * 256;
    const short* f2T_i   = ffn2T + (long)i * 256 * 512;

    // val = f @ val_w[i] (M = L*nq) -> bf16 (LDS-staged, BM=64)
    gemm2_kernel<64, 2, 0, 0><<<dim3(1, kL * kNQ / 64), 256, 0, stream>>>(
        f_bf, 0, kC, valT_i, 256, 256, 1, val_b + (long)i * kE,
        nullptr, val_bf, kE, 0, nullptr, nullptr, nullptr, nullptr,
        nullptr, nullptr, nullptr, nullptr, nullptr);
    // fused softmax + sampling
    sample_kernel<<<kNQ / 8, 256, 0, stream>>>((const unsigned short*)comb_bf,
                                               val_bf, accb);
    // out proj + residual(q fp32) + LN1 -> qbf ; fused FFN1 -> hid_bf
    gemm2_kernel<16, 4, 4, 0><<<dim3(1, kNQ / 16), 256, 0, stream>>>(
        accb, 0, kE, outT_i, 256, 256, 1, out_b + (long)i * kE,
        nullptr, qbf, 256, 0, q, ln1_g + (long)i * kE, ln1_b + (long)i * kE,
        nullptr, nullptr, nullptr, f1T_i, ffn_b1 + (long)i * kFF, hid_bf);
    // FFN2 (K=512) + residual(qbf bf16) + LN2 -> q fp32
    if (i + 1 < kNL) {
      // + fused comb GEMM for layer i+1
      gemm2_kernel<16, 4, 3, 1><<<dim3(1, kNQ / 16), 256, 0, stream>>>(
          hid_bf, 0, kFF, f2T_i, 512, 512, 1, ffn_b2 + (long)i * kE,
          q, nullptr, 256, 0, qbf, ln2_g + (long)i * kE,
          ln2_b + (long)i * kE, nullptr, pos_row, pos_col,
          combT + (long)(i + 1) * 256 * 256, comb_b + (i + 1) * 256, comb_bf);
    } else {
      gemm2_kernel<16, 4, 1, 1><<<dim3(1, kNQ / 16), 256, 0, stream>>>(
          hid_bf, 0, kFF, f2T_i, 512, 512, 1, ffn_b2 + (long)i * kE,
          q, nullptr, 256, 0, qbf, ln2_g + (long)i * kE,
          ln2_b + (long)i * kE, nullptr, nullptr, nullptr,
          nullptr, nullptr, nullptr);
    }
  }

  transpose_kernel<<<dim3(kE / 32, kNQ / 32), 256, 0, stream>>>(q,
                                                                (float*)d_out);
}